// Round 1
// baseline (318.370 us; speedup 1.0000x reference)
//
#include <hip/hip_runtime.h>
#include <hip/hip_bf16.h>

using u16 = unsigned short;
typedef __attribute__((ext_vector_type(8))) short bf16x8;
typedef __attribute__((ext_vector_type(4))) float f32x4;
typedef __attribute__((ext_vector_type(8))) u16 u16x8;
typedef __attribute__((ext_vector_type(4))) u16 u16x4;

#define B_ 2
#define N_ 4096
#define E_ 1024
#define R_ 128
#define H_ 8
#define M_ 8192      // B*N
#define CHUNK_ 128
#define NC_ 32       // N/CHUNK
#define BH_ 16       // B*H

__device__ __forceinline__ float b2f(u16 u) { return __uint_as_float(((unsigned)u) << 16); }
__device__ __forceinline__ u16 f2b(float f) {
  unsigned u = __float_as_uint(f);
  return (u16)((u + 0x7fffu + ((u >> 16) & 1u)) >> 16);   // RNE
}
// fast sigmoid (native v_exp + v_rcp; rel err ~2^-21, fine for bf16 out)
__device__ __forceinline__ float sigm(float x) {
  return __builtin_amdgcn_rcpf(1.0f + __expf(-x));
}

#define GLDS(g, l) __builtin_amdgcn_global_load_lds( \
    (const __attribute__((address_space(1))) unsigned int*)(g), \
    (__attribute__((address_space(3))) unsigned int*)(l), 16, 0, 0)

// ---------------------------------------------------------------------------
// fp32 -> bf16 conversion (x, weights into Wcat/Wcat2/Wo, zero pad).
// ---------------------------------------------------------------------------
struct CvtArgs {
  const float* src[10];
  u16* dst[11];
};

__global__ void __launch_bounds__(256) cvt_all(CvtArgs a) {
  int idx = blockIdx.x * 256 + threadIdx.x;   // float4-granule index; grid exact
  const int SZ[11] = {2097152, 262144, 262144, 262144, 2048,
                      32768, 32768, 32768, 32768, 262144, 30720};
  int off = idx, seg = 0;
#pragma unroll
  for (int i = 0; i < 10; i++) {
    if (seg == i && off >= SZ[i]) { off -= SZ[i]; seg = i + 1; }
  }
  u16x4 z = (u16x4){0, 0, 0, 0};
  if (seg == 10) { ((u16x4*)a.dst[10])[off] = z; return; }   // Wcat pad rows
  float4 v = ((const float4*)a.src[seg])[off];
  u16x4 r;
  r[0] = f2b(v.x); r[1] = f2b(v.y); r[2] = f2b(v.z); r[3] = f2b(v.w);
  if (seg == 6) {              // Wb2 -> Wcat2 rows 0-1023, cols 0-127 (+zero cols 128-255)
    int n = off >> 5, c = off & 31;
    u16x4* W2 = (u16x4*)a.dst[6];
    W2[n * 64 + c] = r; W2[n * 64 + 32 + c] = z;
  } else if (seg == 8) {       // Wg2 -> Wcat2 rows 1024-2047, cols 128-255 (+zero cols 0-127)
    int n = off >> 5, c = off & 31;
    u16x4* W2 = (u16x4*)a.dst[8];
    W2[(1024 + n) * 64 + 32 + c] = r; W2[(1024 + n) * 64 + c] = z;
  } else {
    ((u16x4*)a.dst[seg])[off] = r;
  }
}

// ---------------------------------------------------------------------------
// BK=64 GEMM K-loop, 128x128 tile, 4 waves (kept for bg_gemm / out_gemm).
// ---------------------------------------------------------------------------
template<bool SWAP>
__device__ __forceinline__ void mfma_panel(f32x4 (&acc)[4][4], const u16* A, const u16* Bm,
                                           int wr, int wc, int l15, int q8) {
  bf16x8 af[4], bf[4];
#pragma unroll
  for (int mi = 0; mi < 4; mi++) af[mi] = *(const bf16x8*)&A[(wr * 64 + mi * 16 + l15) * 32 + q8];
#pragma unroll
  for (int ni = 0; ni < 4; ni++) bf[ni] = *(const bf16x8*)&Bm[(wc * 64 + ni * 16 + l15) * 32 + q8];
#pragma unroll
  for (int mi = 0; mi < 4; mi++)
#pragma unroll
    for (int ni = 0; ni < 4; ni++)
      acc[mi][ni] = SWAP
        ? __builtin_amdgcn_mfma_f32_16x16x32_bf16(bf[ni], af[mi], acc[mi][ni], 0, 0, 0)
        : __builtin_amdgcn_mfma_f32_16x16x32_bf16(af[mi], bf[ni], acc[mi][ni], 0, 0, 0);
}

template<bool SWAP, int K>
__device__ __forceinline__ void gemm_loop(const u16* __restrict__ X, const u16* __restrict__ W,
                                          int m0, int n0,
                                          u16* As, u16* Bs, f32x4 (&acc)[4][4], int tid) {
  const int wave = tid >> 6, lane = tid & 63;
  const int wr = wave >> 1, wc = wave & 1, l15 = lane & 15, q8 = (lane >> 4) * 8;
  const u16* Ap = X + (size_t)(m0 + wave * 32 + (lane >> 2)) * K + (lane & 3) * 8;
  const u16* Bp = W + (size_t)(n0 + wave * 32 + (lane >> 2)) * K + (lane & 3) * 8;
  u16* A0 = As + wave * 1024;
  u16* B0 = Bs + wave * 1024;
#pragma unroll
  for (int k0 = 0; k0 < K; k0 += 64) {
    GLDS(Ap + k0,                    A0);
    GLDS(Ap + 16 * (size_t)K + k0,   A0 + 512);
    GLDS(Ap + k0 + 32,               A0 + 4096);
    GLDS(Ap + 16 * (size_t)K + k0 + 32, A0 + 4608);
    GLDS(Bp + k0,                    B0);
    GLDS(Bp + 16 * (size_t)K + k0,   B0 + 512);
    GLDS(Bp + k0 + 32,               B0 + 4096);
    GLDS(Bp + 16 * (size_t)K + k0 + 32, B0 + 4608);
    __syncthreads();
    mfma_panel<SWAP>(acc, As, Bs, wr, wc, l15, q8);
    mfma_panel<SWAP>(acc, As + 4096, Bs + 4096, wr, wc, l15, q8);
    __syncthreads();
  }
}

// ---------------------------------------------------------------------------
// Mega-GEMM, 256x256 tile / BK=64 / 8 waves / 8-phase counted-vmcnt schedule
// (T2 swizzle + T3/T4 + T5). X[M,1024] @ Wcat[3584*,1024]^T, K=1024 = 16
// K-tiles = 8 iterations of 2 K-tiles.
//  * rows 3456..3583 of "Wcat" read adjacent workspace (garbage) - only cols
//    3328-3335 (decay logits) of tile 13 are consumed.
// LDS: A0|B0|A1|B1, each 32 KB, [256 rows][64 cols] bf16 (B rows permuted so
// each 64-row staging call is contiguous). 16-B slot swizzle: slot ^= (row&7),
// applied by pre-swizzling the per-lane GLOBAL source (gload_lds dest is
// linear) and XORing the ds_read address the same way -> conflict-free b128.
// Swapped MFMA everywhere: acc[mi][ni][r] = C[m = wr*128+(mi>>2)*64+(mi&3)*16
// + l15][n = wc*64+(ni>>1)*32+(ni&1)*16+q4+r].
// Tiles: 0-3 Q(silu), 4-7 K(silu + KT via LDS transpose), 8-11 V(VT via LDS
// transpose), 12 T1(raw), 13 LOGF.
// ---------------------------------------------------------------------------
__global__ void __launch_bounds__(512, 2) mega_gemm256(
    const u16* __restrict__ X, const u16* __restrict__ Wcat,
    const float* __restrict__ llb,
    u16* __restrict__ Qb, u16* __restrict__ Kb,
    u16* __restrict__ KT, u16* __restrict__ VT,
    u16* __restrict__ T1, float* __restrict__ LOGF) {
  __shared__ u16 sh[65536];          // 128 KiB
  const int tid = threadIdx.x;
  const int w = tid >> 6, lane = tid & 63;
  const int wr = w >> 2, wc = w & 3;
  const int l15 = lane & 15, g = lane >> 4;
  const int l7 = l15 & 7;

  // bijective XCD swizzle (448 % 8 == 0), nt fast within each XCD chunk
  int flat = blockIdx.x;
  int swz = (flat & 7) * 56 + (flat >> 3);
  const int nt = swz % 14, mt = swz / 14;
  const int m0 = mt * 256, n0 = nt * 256;

  u16* const A0 = sh;
  u16* const B0 = sh + 16384;
  u16* const A1 = sh + 32768;
  u16* const B1 = sh + 49152;
  u16* const bufA[2] = {A0, A1};
  u16* const bufB[2] = {B0, B1};

  // ---- staging source pointers (k=0), swizzle pre-applied to source col ----
  const int lrow = lane >> 3;                  // 0..7
  const int lcol = ((lane & 7) ^ lrow) * 8;    // u16 offset in 64-col K-tile
  const int rbA[4] = {0, 128, 64, 192};        // {Aα0,Aα1,Aβ0,Aβ1} lds rowbases
  const int rbB[4] = {0, 64, 128, 192};        // {Bα0,Bα1,Bβ0,Bβ1} lds ρ-bases
  const u16* pA[4];
  const u16* pB[4];
#pragma unroll
  for (int c = 0; c < 4; c++) {
    pA[c] = X + (size_t)(m0 + rbA[c] + w * 8 + lrow) * 1024 + lcol;
    int rho = rbB[c] + w * 8 + lrow;           // permuted B lds row
    int nh = rho >> 7, rr = rho & 127;
    int nsrc = nh * 32 + ((rr >> 5) << 6) + (rr & 31);
    pB[c] = Wcat + (size_t)(n0 + nsrc) * 1024 + lcol;
  }

  // ds_read per-thread bases (bytes)
  const int arow = (wr * 128 + l15) * 128;
  const int brow = (wc * 32 + l15) * 128;
  const int sA0 = (g ^ l7) << 4;               // ksub 0 slot (swizzled)
  const int sA1 = sA0 ^ 64;                    // ksub 1

  f32x4 acc[8][4];
#pragma unroll
  for (int i = 0; i < 8; i++)
#pragma unroll
    for (int j = 0; j < 4; j++) acc[i][j] = (f32x4){0.f, 0.f, 0.f, 0.f};

#define SA(T, c) GLDS(pA[c] + (size_t)(T) * 64, \
    (u16*)((char*)bufA[(T) & 1] + rbA[c] * 128 + w * 1024))
#define SB(T, c) GLDS(pB[c] + (size_t)(T) * 64, \
    (u16*)((char*)bufB[(T) & 1] + rbB[c] * 128 + w * 1024))

#define PHASE(Ab, Bb, MH, NH, STAGES, WAITOP)                                   \
  {                                                                             \
    bf16x8 af[4][2], bf[2][2];                                                  \
    const char* Abase = (const char*)(Ab) + arow + (MH) * 8192;                 \
    const char* Bbase = (const char*)(Bb) + brow + (NH) * 16384;                \
    _Pragma("unroll") for (int mi2 = 0; mi2 < 4; mi2++) {                       \
      af[mi2][0] = *(const bf16x8*)(Abase + mi2 * 2048 + sA0);                  \
      af[mi2][1] = *(const bf16x8*)(Abase + mi2 * 2048 + sA1);                  \
    }                                                                           \
    _Pragma("unroll") for (int ni2 = 0; ni2 < 2; ni2++) {                       \
      bf[ni2][0] = *(const bf16x8*)(Bbase + ni2 * 2048 + sA0);                  \
      bf[ni2][1] = *(const bf16x8*)(Bbase + ni2 * 2048 + sA1);                  \
    }                                                                           \
    STAGES;                                                                     \
    __builtin_amdgcn_sched_barrier(0);                                          \
    __builtin_amdgcn_s_barrier();                                               \
    asm volatile("s_waitcnt lgkmcnt(0)" ::: "memory");                          \
    __builtin_amdgcn_sched_barrier(0);                                          \
    __builtin_amdgcn_s_setprio(1);                                              \
    _Pragma("unroll") for (int mi2 = 0; mi2 < 4; mi2++)                         \
      _Pragma("unroll") for (int ni2 = 0; ni2 < 2; ni2++) {                     \
        acc[(MH)*4+mi2][(NH)*2+ni2] = __builtin_amdgcn_mfma_f32_16x16x32_bf16(  \
            bf[ni2][0], af[mi2][0], acc[(MH)*4+mi2][(NH)*2+ni2], 0, 0, 0);      \
        acc[(MH)*4+mi2][(NH)*2+ni2] = __builtin_amdgcn_mfma_f32_16x16x32_bf16(  \
            bf[ni2][1], af[mi2][1], acc[(MH)*4+mi2][(NH)*2+ni2], 0, 0, 0);      \
      }                                                                         \
    __builtin_amdgcn_s_setprio(0);                                              \
    WAITOP;                                                                     \
    __builtin_amdgcn_sched_barrier(0);                                          \
    __builtin_amdgcn_s_barrier();                                               \
    __builtin_amdgcn_sched_barrier(0);                                          \
  }

#define NOOP ((void)0)
// Half-tile ledger (tile 2i in buf0 read ph0-3, tile 2i+1 in buf1 read ph4-7;
// staged region is fully consumed one phase before its stage issue; vmcnt(4)
// at ph3/ph7 leaves exactly the last 2 staged halves in flight and certifies
// the next tile fully landed before its first read):
#define ITER(i, LAST)                                                           \
  PHASE(A0, B0, 0, 0, { SA(2*(i)+1, 2); SA(2*(i)+1, 3); }, NOOP);               \
  PHASE(A0, B0, 0, 1, { SB(2*(i)+1, 2); SB(2*(i)+1, 3); }, NOOP);               \
  PHASE(A0, B0, 1, 0, { if (!(LAST)) { SA(2*(i)+2, 0); SA(2*(i)+2, 1); } }, NOOP); \
  PHASE(A0, B0, 1, 1, { if (!(LAST)) { SB(2*(i)+2, 0); SB(2*(i)+2, 1); } },     \
        { if (LAST) { asm volatile("s_waitcnt vmcnt(0)" ::: "memory"); }        \
          else      { asm volatile("s_waitcnt vmcnt(4)" ::: "memory"); } });    \
  PHASE(A1, B1, 0, 0, { if (!(LAST)) { SA(2*(i)+2, 2); SA(2*(i)+2, 3); } }, NOOP); \
  PHASE(A1, B1, 0, 1, { if (!(LAST)) { SB(2*(i)+2, 2); SB(2*(i)+2, 3); } }, NOOP); \
  PHASE(A1, B1, 1, 0, { if (!(LAST)) { SA(2*(i)+3, 0); SA(2*(i)+3, 1); } }, NOOP); \
  PHASE(A1, B1, 1, 1, { if (!(LAST)) { SB(2*(i)+3, 0); SB(2*(i)+3, 1); } },     \
        { if (!(LAST)) { asm volatile("s_waitcnt vmcnt(4)" ::: "memory"); } });

  // prologue: tile 0 complete + tile 1 alpha halves; land tile 0, keep 4 in flight
  SA(0, 0); SA(0, 1); SB(0, 0); SB(0, 1);
  SA(0, 2); SA(0, 3); SB(0, 2); SB(0, 3);
  SA(1, 0); SA(1, 1); SB(1, 0); SB(1, 1);
  asm volatile("s_waitcnt vmcnt(4)" ::: "memory");
  __builtin_amdgcn_sched_barrier(0);
  __builtin_amdgcn_s_barrier();
  __builtin_amdgcn_sched_barrier(0);

#pragma unroll 1
  for (int i = 0; i < 7; ++i) {
    ITER(i, 0)
  }
  ITER(7, 1)

#undef ITER
#undef PHASE
#undef SA
#undef SB
#undef NOOP

  // ------------------------------- epilogue --------------------------------
  const int q4 = g * 4;
  const int b = m0 >> 12;
  const int nseq0 = m0 & (N_ - 1);

  if (nt < 4) {                     // Q: silu -> Qb[m][n]
#pragma unroll
    for (int mi = 0; mi < 8; mi++) {
      size_t mrow = (size_t)(m0 + wr * 128 + (mi >> 2) * 64 + (mi & 3) * 16 + l15);
#pragma unroll
      for (int ni = 0; ni < 4; ni++) {
        int nc = n0 + wc * 64 + (ni >> 1) * 32 + (ni & 1) * 16 + q4;
        u16x4 pk;
#pragma unroll
        for (int r = 0; r < 4; r++) { float v = acc[mi][ni][r]; pk[r] = f2b(v * sigm(v)); }
        *(u16x4*)&Qb[mrow * E_ + nc] = pk;
      }
    }
    return;
  }
  if (nt == 12) {                   // T1: raw
#pragma unroll
    for (int mi = 0; mi < 8; mi++) {
      size_t mrow = (size_t)(m0 + wr * 128 + (mi >> 2) * 64 + (mi & 3) * 16 + l15);
#pragma unroll
      for (int ni = 0; ni < 4; ni++) {
        int nc = n0 - 3072 + wc * 64 + (ni >> 1) * 32 + (ni & 1) * 16 + q4;
        u16x4 pk;
#pragma unroll
        for (int r = 0; r < 4; r++) pk[r] = f2b(acc[mi][ni][r]);
        *(u16x4*)&T1[mrow * 256 + nc] = pk;
      }
    }
    return;
  }
  if (nt == 13) {                   // decay logits (cols 3328-3335) -> LOGF
    if (wc == 0 && g < 2) {
#pragma unroll
      for (int mi = 0; mi < 8; mi++) {
        int nseq = nseq0 + wr * 128 + (mi >> 2) * 64 + (mi & 3) * 16 + l15;
#pragma unroll
        for (int r = 0; r < 4; r++) {
          int h = q4 + r;           // 0..7
          float lb = __expf(llb[h]);
          LOGF[(size_t)(b * H_ + h) * N_ + nseq] =
              __logf(lb + (1.f - lb) * sigm(acc[mi][0][r]));
        }
      }
    }
    return;
  }

  // K (4-7) / V (8-11): transpose 256x256 tile through LDS -> KT / VT
  const bool isK = nt < 8;
  if (isK) {                        // Kb row-major store (silu)
#pragma unroll
    for (int mi = 0; mi < 8; mi++) {
      size_t mrow = (size_t)(m0 + wr * 128 + (mi >> 2) * 64 + (mi & 3) * 16 + l15);
#pragma unroll
      for (int ni = 0; ni < 4; ni++) {
        int nc = n0 - 1024 + wc * 64 + (ni >> 1) * 32 + (ni & 1) * 16 + q4;
        u16x4 pk;
#pragma unroll
        for (int r = 0; r < 4; r++) { float v = acc[mi][ni][r]; pk[r] = f2b(v * sigm(v)); }
        *(u16x4*)&Kb[mrow * E_ + nc] = pk;
      }
    }
  }
  u16* Ts = sh;                     // [256 n][136] overlay on main LDS
  u16* DST = isK ? KT : VT;
  const int head0 = (n0 - (isK ? 1024 : 2048)) >> 7;
  __syncthreads();
#pragma unroll
  for (int pass = 0; pass < 2; pass++) {   // pass = m-half (wr)
    if (wr == pass) {
#pragma unroll
      for (int mi = 0; mi < 8; mi++) {
        int ml = (mi >> 2) * 64 + (mi & 3) * 16 + l15;  // 0..127 in this half
#pragma unroll
        for (int ni = 0; ni < 4; ni++) {
          int nl = wc * 64 + (ni >> 1) * 32 + (ni & 1) * 16 + q4;
#pragma unroll
          for (int r = 0; r < 4; r++) {
            float v = acc[mi][ni][r];
            if (isK) v = v * sigm(v);
            Ts[(nl + r) * 136 + ml] = f2b(v);
          }
        }
      }
    }
    __syncthreads();
    {
      int row = tid >> 1;                  // n-local 0..255
      int colb = (tid & 1) * 64;           // m-local base within half
      size_t drow = ((size_t)(b * H_ + head0 + (row >> 7)) * R_ + (row & 127)) * (size_t)N_;
      size_t seqb = (size_t)nseq0 + pass * 128 + colb;
#pragma unroll
      for (int j = 0; j < 8; j++) {
        u16x8 v = *(const u16x8*)&Ts[row * 136 + colb + j * 8];
        *(u16x8*)&DST[drow + seqb + j * 8] = v;
      }
    }
    if (pass == 0) __syncthreads();
  }
}

// ---------------------------------------------------------------------------
// beta+gate GEMM (swapped): T1[M,256] @ Wcat2[2048,256]^T.
// ---------------------------------------------------------------------------
__global__ void __launch_bounds__(256) bg_gemm(const u16* __restrict__ T1, const u16* __restrict__ W2,
                                               u16* __restrict__ BETA, u16* __restrict__ GATE) {
  __shared__ u16 As[8192];
  __shared__ u16 Bs[8192];
  const int tid = threadIdx.x;
  const int m0 = blockIdx.x * 128;
  const int n0 = blockIdx.y * 128;
  f32x4 acc[4][4];
#pragma unroll
  for (int i = 0; i < 4; i++)
#pragma unroll
    for (int j = 0; j < 4; j++) acc[i][j] = (f32x4){0.f, 0.f, 0.f, 0.f};
  gemm_loop<true, 256>(T1, W2, m0, n0, As, Bs, acc, tid);
  const int wave = tid >> 6, lane = tid & 63;
  const int wr = wave >> 1, wc = wave & 1, l15 = lane & 15, q4 = (lane >> 4) * 4;
#pragma unroll
  for (int mi = 0; mi < 4; mi++) {
#pragma unroll
    for (int ni = 0; ni < 4; ni++) {
      int nb = n0 + wc * 64 + ni * 16 + q4;
      int mcol = m0 + wr * 64 + mi * 16 + l15;
      u16x4 pk;
      if (nb < 1024) {
#pragma unroll
        for (int r = 0; r < 4; r++) {
          float v = acc[mi][ni][r];
          pk[r] = f2b(v * sigm(v));
        }
        *(u16x4*)&BETA[(size_t)mcol * E_ + nb] = pk;
      } else {
#pragma unroll
        for (int r = 0; r < 4; r++) pk[r] = f2b(sigm(acc[mi][ni][r]));
        *(u16x4*)&GATE[(size_t)mcol * E_ + nb - 1024] = pk;
      }
    }
  }
}

// ---------------------------------------------------------------------------
// Output GEMM (swapped): OLN[M,1024] @ Wo[1024,1024]^T -> fp32 out, float4.
// ---------------------------------------------------------------------------
__global__ void __launch_bounds__(256) out_gemm(const u16* __restrict__ X, const u16* __restrict__ W,
                                                float* __restrict__ C) {
  __shared__ u16 As[8192];
  __shared__ u16 Bs[8192];
  const int tid = threadIdx.x;
  const int m0 = blockIdx.x * 128;
  const int n0 = blockIdx.y * 128;
  f32x4 acc[4][4];
#pragma unroll
  for (int i = 0; i < 4; i++)
#pragma unroll
    for (int j = 0; j < 4; j++) acc[i][j] = (f32x4){0.f, 0.f, 0.f, 0.f};
  gemm_loop<true, 1024>(X, W, m0, n0, As, Bs, acc, tid);
  const int wave = tid >> 6, lane = tid & 63;
  const int wr = wave >> 1, wc = wave & 1, l15 = lane & 15, q4 = (lane >> 4) * 4;
#pragma unroll
  for (int mi = 0; mi < 4; mi++) {
#pragma unroll
    for (int ni = 0; ni < 4; ni++) {
      int nb = n0 + wc * 64 + ni * 16 + q4;
      int mcol = m0 + wr * 64 + mi * 16 + l15;
      *(f32x4*)&C[(size_t)mcol * E_ + nb] = acc[mi][ni];
    }
  }
}

// ---------------------------------------------------------------------------
// Householder on bf16 q (in place)
// ---------------------------------------------------------------------------
__global__ void __launch_bounds__(256) householder(u16* __restrict__ Q, const u16* __restrict__ BETA) {
  int row = blockIdx.x;
  int tid = threadIdx.x;
  u16* q = Q + (size_t)row * E_;
  const u16* bt = BETA + (size_t)row * E_;
  u16x4 q4 = *(const u16x4*)(q + tid * 4);
  u16x4 b4 = *(const u16x4*)(bt + tid * 4);
  float qv[4], bv[4];
#pragma unroll
  for (int i = 0; i < 4; i++) { qv[i] = b2f(q4[i]); bv[i] = b2f(b4[i]); }
  float ss = bv[0]*bv[0] + bv[1]*bv[1] + bv[2]*bv[2] + bv[3]*bv[3];
  float qd = qv[0]*bv[0] + qv[1]*bv[1] + qv[2]*bv[2] + qv[3]*bv[3];
  __shared__ float red[8];
#pragma unroll
  for (int m = 1; m < 64; m <<= 1) { ss += __shfl_xor(ss, m); qd += __shfl_xor(qd, m); }
  int wid = tid >> 6;
  if ((tid & 63) == 0) { red[wid] = ss; red[4 + wid] = qd; }
  __syncthreads();
  ss = red[0] + red[1] + red[2] + red[3];
  qd = red[4] + red[5] + red[6] + red[7];
  float coef = 2.f * qd / (ss + 1e-12f);
  const float scale = 0.08838834764831845f;  // 128^-0.5 folded in
  u16x4 o4;
#pragma unroll
  for (int i = 0; i < 4; i++) o4[i] = f2b((qv[i] - coef * bv[i]) * scale);
  *(u16x4*)(q + tid * 4) = o4;
}

// inclusive scan of the 128 log-decay values of one chunk into cum[] (wave 0)
__device__ __forceinline__ void scan_chunk(const float* __restrict__ lf, float* cum, int tid) {
  if (tid < 64) {
    float a = lf[tid], b = lf[tid + 64];
#pragma unroll
    for (int off = 1; off < 64; off <<= 1) {
      float t = __shfl_up(a, off);  if (tid >= off) a += t;
      float t2 = __shfl_up(b, off); if (tid >= off) b += t2;
    }
    b += __shfl(a, 63);
    cum[tid] = a; cum[tid + 64] = b;
  }
  __syncthreads();
}

// stage a [128 x 32] bf16 slab (row stride `stride` elements) into LDS [128][40]
__device__ __forceinline__ void stage32(u16* dst, const u16* src, size_t stride, int tid) {
  int r0 = tid >> 2, c8 = (tid & 3) * 8;
  *(u16x8*)&dst[(size_t)r0 * 40 + c8] = *(const u16x8*)&src[(size_t)r0 * stride + c8];
  int r1 = r0 + 64;
  *(u16x8*)&dst[(size_t)r1 * 40 + c8] = *(const u16x8*)&src[(size_t)r1 * stride + c8];
}

// same, scaling column j (slab-local) by w[j0 + j]
__device__ __forceinline__ void stage32_scaled(u16* dst, const u16* src, size_t stride,
                                               const float* w, int j0, int tid) {
  int c8 = (tid & 3) * 8;
  float wv[8];
#pragma unroll
  for (int i = 0; i < 8; i++) wv[i] = w[j0 + c8 + i];
#pragma unroll
  for (int rr = 0; rr < 128; rr += 64) {
    int r = rr + (tid >> 2);
    u16x8 raw = *(const u16x8*)&src[(size_t)r * stride + c8];
    u16x8 o;
#pragma unroll
    for (int i = 0; i < 8; i++) o[i] = f2b(b2f(raw[i]) * wv[i]);
    *(u16x8*)&dst[(size_t)r * 40 + c8] = o;
  }
}

// one K=32 MFMA step over a 128x128 output (4 waves), A/B slabs in LDS [128][40]
template<bool SWAP>
__device__ __forceinline__ void mfma16(f32x4 (&acc)[4][4], const u16* A, const u16* Bm,
                                       int wr, int wc, int l15, int q8) {
  bf16x8 af[4], bf[4];
#pragma unroll
  for (int mi = 0; mi < 4; mi++) af[mi] = *(const bf16x8*)&A[(wr * 64 + mi * 16 + l15) * 40 + q8];
#pragma unroll
  for (int ni = 0; ni < 4; ni++) bf[ni] = *(const bf16x8*)&Bm[(wc * 64 + ni * 16 + l15) * 40 + q8];
#pragma unroll
  for (int mi = 0; mi < 4; mi++)
#pragma unroll
    for (int ni = 0; ni < 4; ni++)
      acc[mi][ni] = SWAP
        ? __builtin_amdgcn_mfma_f32_16x16x32_bf16(bf[ni], af[mi], acc[mi][ni], 0, 0, 0)
        : __builtin_amdgcn_mfma_f32_16x16x32_bf16(af[mi], bf[ni], acc[mi][ni], 0, 0, 0);
}

// ---------------------------------------------------------------------------
// Phase A (MFMA, swapped): acc[mi][ni][r] = D[k = wc*64+ni*16+q4+r][v = wr*64+mi*16+l15]
// = sum_j KTw[k][j] VT[v][j]  ->  u16x4 (bf16) store at U[v][k..k+3].
// ---------------------------------------------------------------------------
__global__ void __launch_bounds__(256) gla_phaseA(const u16* __restrict__ KT, const u16* __restrict__ VT,
                                                  const float* __restrict__ LOGF,
                                                  u16* __restrict__ U, float* __restrict__ DC) {
  const int blk = blockIdx.x;
  const int bh = blk >> 5, c = blk & 31;
  const int tid = threadIdx.x;
  const int wave = tid >> 6, lane = tid & 63;
  const int wr = wave >> 1, wc = wave & 1, l15 = lane & 15, q8 = (lane >> 4) * 8;
  __shared__ u16 SA[128 * 40];
  __shared__ u16 SB[128 * 40];
  __shared__ float cum[CHUNK_];
  __shared__ float wd[CHUNK_];
  scan_chunk(LOGF + (size_t)bh * N_ + c * CHUNK_, cum, tid);
  if (tid < 128) wd[tid] = __expf(cum[127] - cum[tid]);
  __syncthreads();
  const u16* vbase = VT + ((size_t)bh * R_) * N_ + (size_t)c * CHUNK_;
  const u16* kbase = KT + ((size_t)bh * R_) * N_ + (size_t)c * CHUNK_;
  f32x4 acc[4][4];
#pragma unroll
  for (int i = 0; i < 4; i++)
#pragma unroll
    for (int j = 0; j < 4; j++) acc[i][j] = (f32x4){0.f, 0.f, 0.f, 0.f};
  for (int j0 = 0; j0 < CHUNK_; j0 += 32) {
    __syncthreads();
    stage32(SA, vbase + j0, N_, tid);
    stage32_scaled(SB, kbase + j0, N_, wd, j0, tid);
    __syncthreads();
    mfma16<true>(acc, SA, SB, wr, wc, l15, q8);
  }
  u16* Up = U + (size_t)blk * (R_ * R_);
  const int q4 = (lane >> 4) * 4;
#pragma unroll
  for (int mi = 0; mi < 4; mi++) {
#pragma unroll
    for (int ni = 0; ni < 4; ni++) {
      int v = wr * 64 + mi * 16 + l15;
      int kb = wc * 64 + ni * 16 + q4;
      u16x4 pk;
#pragma unroll
      for (int r = 0; r < 4; r++) pk[r] = f2b(acc[mi][ni][r]);
      *(u16x4*)&Up[(size_t)v * R_ + kb] = pk;
    }
  }
  if (tid == 0) DC[blk] = __expf(cum[127]);
}

// ---------------------------------------------------------------------------
// Phase B: propagate chunk-start states; U bf16 [v][k] -> SS bf16 [v][k]
// ---------------------------------------------------------------------------
__global__ void __launch_bounds__(256) gla_phaseB(const u16* __restrict__ U, const float* __restrict__ DC,
                                                  u16* __restrict__ SSb) {
  int idx = blockIdx.x * 256 + threadIdx.x;
  int bh = idx >> 14;
  int e = idx & 16383;
  float s = 0.f;
  for (int c = 0; c < NC_; c++) {
    size_t off = ((size_t)bh * NC_ + c) * 16384 + e;
    SSb[off] = f2b(s);
    s = DC[bh * NC_ + c] * s + b2f(U[off]);
  }
}

// ---------------------------------------------------------------------------
// Phase C (MFMA): o_i = exp(cum_i)*q_i@Sstart + sum_{j<=i} exp(cum_i-cum_j)(q_i.k_j) v_j
// ---------------------------------------------------------------------------
__global__ void __launch_bounds__(256) gla_phaseC(const u16* __restrict__ Qb, const u16* __restrict__ Kb,
                                                  const u16* __restrict__ VT, const u16* __restrict__ SSb,
                                                  const float* __restrict__ LOGF, u16* __restrict__ Ob) {
  const int blk = blockIdx.x;
  const int bh = blk >> 5, c = blk & 31;
  const int b = bh >> 3, h = bh & 7;
  const int tid = threadIdx.x;
  const int wave = tid >> 6, lane = tid & 63;
  const int wr = wave >> 1, wc = wave & 1, l15 = lane & 15;
  const int q4i = (lane >> 4) * 4, q8 = (lane >> 4) * 8;
  __shared__ u16 SA[128 * 40];
  __shared__ u16 SB[128 * 40];
  __shared__ u16 Ps[128 * 136];
  __shared__ float cum[CHUNK_];
  __shared__ float cumE[CHUNK_];
  scan_chunk(LOGF + (size_t)bh * N_ + c * CHUNK_, cum, tid);
  if (tid < 128) cumE[tid] = __expf(cum[tid]);
  __syncthreads();
  const size_t rowbase = ((size_t)(b * N_ + c * CHUNK_)) * E_ + (size_t)h * R_;
  const u16* vtbase = VT + ((size_t)bh * R_) * N_ + (size_t)c * CHUNK_;
  const u16* ssbase = SSb + (size_t)blk * (R_ * R_);

  f32x4 acc[4][4];
#pragma unroll
  for (int i = 0; i < 4; i++)
#pragma unroll
    for (int j = 0; j < 4; j++) acc[i][j] = (f32x4){0.f, 0.f, 0.f, 0.f};

  // ---- S^T = K @ Q^T (row=j, col=i) ----
  for (int r0 = 0; r0 < R_; r0 += 32) {
    __syncthreads();
    stage32(SA, Kb + rowbase + r0, E_, tid);   // rows j
    stage32(SB, Qb + rowbase + r0, E_, tid);   // rows i
    __syncthreads();
    mfma16<false>(acc, SA, SB, wr, wc, l15, q8);
  }
  // ---- mask + decay -> Ps[i][j] ----
#pragma unroll
  for (int mi = 0; mi < 4; mi++) {
#pragma unroll
    for (int ni = 0; ni < 4; ni++) {
      int jb = wr * 64 + mi * 16 + q4i;
      int i = wc * 64 + ni * 16 + l15;
      float ci = cum[i];
      float4 cj = *(const float4*)&cum[jb];
      u16x4 pk;
      float cjv[4] = {cj.x, cj.y, cj.z, cj.w};
#pragma unroll
      for (int r = 0; r < 4; r++) {
        int j = jb + r;
        float w = (j <= i) ? __expf(ci - cjv[r]) : 0.f;
        pk[r] = f2b(acc[mi][ni][r] * w);
      }
      *(u16x4*)&Ps[i * 136 + jb] = pk;
    }
  }
  // ---- term1 (swapped): Q @ SS^T  (row=v, col=i) ----
#pragma unroll
  for (int i = 0; i < 4; i++)
#pragma unroll
    for (int j = 0; j < 4; j++) acc[i][j] = (f32x4){0.f, 0.f, 0.f, 0.f};
  for (int k0 = 0; k0 < R_; k0 += 32) {
    __syncthreads();
    stage32(SA, Qb + rowbase + k0, E_, tid);     // rows i
    stage32(SB, ssbase + k0, R_, tid);           // rows v (SS^T layout [v][k])
    __syncthreads();
    mfma16<true>(acc, SA, SB, wr, wc, l15, q8);
  }
  // scale by exp(cum_i)
#pragma unroll
  for (int mi = 0; mi < 4; mi++) {
    float ei = cumE[wr * 64 + mi * 16 + l15];
#pragma unroll
    for (int ni = 0; ni < 4; ni++)
#pragma unroll
      for (int r = 0; r < 4; r++) acc[mi][ni][r] *= ei;
  }
  // ---- term2 (swapped): acc += P @ V^T (row=v, col=i) ----
  for (int j0 = 0; j0 < CHUNK_; j0 += 32) {
    __syncthreads();
    stage32(SB, vtbase + j0, N_, tid);           // rows v
    __syncthreads();
    if (wr == 1 || j0 < 64) {                    // wr==0 waves: i<64 -> j>=64 all masked
      bf16x8 af[4], bf[4];
#pragma unroll
      for (int mi = 0; mi < 4; mi++)
        af[mi] = *(const bf16x8*)&Ps[(wr * 64 + mi * 16 + l15) * 136 + j0 + q8];
#pragma unroll
      for (int ni = 0; ni < 4; ni++)
        bf[ni] = *(const bf16x8*)&SB[(wc * 64 + ni * 16 + l15) * 40 + q8];
#pragma unroll
      for (int mi = 0; mi < 4; mi++)
#pragma unroll
        for (int ni = 0; ni < 4; ni++)
          acc[mi][ni] = __builtin_amdgcn_mfma_f32_16x16x32_bf16(bf[ni], af[mi], acc[mi][ni], 0, 0, 0);
    }
  }
  // ---- write O (bf16, row-major [m][E]): u16x4 along v at fixed i ----
#pragma unroll
  for (int mi = 0; mi < 4; mi++) {
#pragma unroll
    for (int ni = 0; ni < 4; ni++) {
      int i = wr * 64 + mi * 16 + l15;
      int vb = wc * 64 + ni * 16 + q4i;
      u16x4 pk;
#pragma unroll
      for (int r = 0; r < 4; r++) pk[r] = f2b(acc[mi][ni][r]);
      *(u16x4*)&Ob[rowbase + (size_t)i * E_ + vb] = pk;
    }
  }
}

// ---------------------------------------------------------------------------
// o = o * gate (both bf16); LayerNorm(weight-only, fp32 gamma) -> bf16
// ---------------------------------------------------------------------------
__global__ void __launch_bounds__(256) gate_ln(const u16* __restrict__ O, const u16* __restrict__ G,
                                               const float* __restrict__ gamma, u16* __restrict__ OLN) {
  int row = blockIdx.x, tid = threadIdx.x;
  u16x4 o4 = *(const u16x4*)(O + (size_t)row * E_ + tid * 4);
  u16x4 g4 = *(const u16x4*)(G + (size_t)row * E_ + tid * 4);
  float x0 = b2f(o4[0]) * b2f(g4[0]), x1 = b2f(o4[1]) * b2f(g4[1]);
  float x2 = b2f(o4[2]) * b2f(g4[2]), x3 = b2f(o4[3]) * b2f(g4[3]);
  float s = x0 + x1 + x2 + x3;
  float sq = x0 * x0 + x1 * x1 + x2 * x2 + x3 * x3;
  __shared__ float red[8];
#pragma unroll
  for (int m = 1; m < 64; m <<= 1) { s += __shfl_xor(s, m); sq += __shfl_xor(sq, m); }
  int wid = tid >> 6;
  if ((tid & 63) == 0) { red[wid] = s; red[4 + wid] = sq; }
  __syncthreads();
  s = red[0] + red[1] + red[2] + red[3];
  sq = red[4] + red[5] + red[6] + red[7];
  float mu = s * (1.f / 1024.f);
  float var = sq * (1.f / 1024.f) - mu * mu;
  float rs = rsqrtf(var + 1e-5f);
  int e = tid * 4;
  u16x4 r4;
  r4[0] = f2b((x0 - mu) * rs * gamma[e + 0]);
  r4[1] = f2b((x1 - mu) * rs * gamma[e + 1]);
  r4[2] = f2b((x2 - mu) * rs * gamma[e + 2]);
  r4[3] = f2b((x3 - mu) * rs * gamma[e + 3]);
  *(u16x4*)(OLN + (size_t)row * E_ + e) = r4;
}

// ---------------------------------------------------------------------------
extern "C" void kernel_launch(void* const* d_in, const int* in_sizes, int n_in,
                              void* d_out, int out_size, void* d_ws, size_t ws_size,
                              hipStream_t stream) {
  (void)in_sizes; (void)n_in; (void)out_size; (void)ws_size;
  const float* x   = (const float*)d_in[0];
  const float* llb = (const float*)d_in[1];
  const float* Wq  = (const float*)d_in[2];
  const float* Wk  = (const float*)d_in[3];
  const float* Wv  = (const float*)d_in[4];
  const float* Wf  = (const float*)d_in[5];
  const float* Wb1 = (const float*)d_in[6];
  const float* Wb2 = (const float*)d_in[7];
  const float* Wg1 = (const float*)d_in[8];
  const float* Wg2 = (const float*)d_in[9];
  const float* gm  = (const float*)d_in[10];
  const float* Wo  = (const float*)d_in[11];
  float* out = (float*)d_out;

  char* ws = (char*)d_ws;
  const size_t SZB = (size_t)M_ * E_ * 2;            // 16.78 MB bf16 [M,E]
  u16*   Qb    = (u16*)(ws + 0 * SZB);               // q bf16 (OLN overlay later)
  u16*   Kb    = (u16*)(ws + 1 * SZB);
  u16*   KT    = (u16*)(ws + 2 * SZB);               // [B,H,R,N]
  u16*   VT    = (u16*)(ws + 3 * SZB);               // [B,H,R,N]
  u16*   BETAb = (u16*)(ws + 4 * SZB);               // beta -> O overlay
  u16*   GATEb = (u16*)(ws + 5 * SZB);
  u16*   SSb   = (u16*)(ws + 6 * SZB);               // chunk-start states bf16 [v][k]
  u16*   XB    = (u16*)(ws + 7 * SZB);
  u16*   U     = (u16*)(ws + 8 * SZB);               // bf16 [512][128][128]
  char*  tail  = ws + 8 * SZB + (size_t)BH_ * NC_ * R_ * R_ * 2;
  u16*   Wcat  = (u16*)tail;                         // [3456][1024]
  u16*   Wcat2 = Wcat + (size_t)3456 * 1024;         // [2048][256]
  u16*   WOb   = Wcat2 + (size_t)2048 * 256;         // [1024][1024]
  u16*   T1    = WOb + (size_t)E_ * E_;              // [M,256]
  float* LOGF  = (float*)(T1 + (size_t)M_ * 256);
  float* DC    = LOGF + (size_t)BH_ * N_;
  u16*   Ob    = BETAb;                              // overlay (beta dead after householder)
  u16*   OLN   = Qb;                                 // overlay (q dead after phaseC)

  CvtArgs ca;
  ca.src[0] = x;   ca.dst[0]  = XB;
  ca.src[1] = Wq;  ca.dst[1]  = Wcat;
  ca.src[2] = Wk;  ca.dst[2]  = Wcat + (size_t)1024 * 1024;
  ca.src[3] = Wv;  ca.dst[3]  = Wcat + (size_t)2048 * 1024;
  ca.src[4] = Wf;  ca.dst[4]  = Wcat + (size_t)3328 * 1024;
  ca.src[5] = Wb1; ca.dst[5]  = Wcat + (size_t)3072 * 1024;
  ca.src[6] = Wb2; ca.dst[6]  = Wcat2;
  ca.src[7] = Wg1; ca.dst[7]  = Wcat + (size_t)3200 * 1024;
  ca.src[8] = Wg2; ca.dst[8]  = Wcat2;
  ca.src[9] = Wo;  ca.dst[9]  = WOb;
  ca.dst[10] = Wcat + (size_t)3336 * 1024;           // zero pad rows

  dim3 blk(256);
  cvt_all<<<dim3(12928), blk, 0, stream>>>(ca);
  mega_gemm256<<<dim3(448), dim3(512), 0, stream>>>(XB, Wcat, llb, Qb, Kb, KT, VT, T1, LOGF);
  bg_gemm<<<dim3(64, 16), blk, 0, stream>>>(T1, Wcat2, BETAb, GATEb);
  householder<<<dim3(M_), blk, 0, stream>>>(Qb, BETAb);
  gla_phaseA<<<dim3(BH_ * NC_), blk, 0, stream>>>(KT, VT, LOGF, U, DC);
  gla_phaseB<<<dim3(BH_ * 16384 / 256), blk, 0, stream>>>(U, DC, SSb);
  gla_phaseC<<<dim3(BH_ * NC_), blk, 0, stream>>>(Qb, Kb, VT, SSb, LOGF, Ob);
  gate_ln<<<dim3(M_), blk, 0, stream>>>(Ob, GATEb, gm, OLN);
  out_gemm<<<dim3(64, 8), blk, 0, stream>>>(OLN, WOb, out);
}

// Round 2
// 313.909 us; speedup vs baseline: 1.0142x; 1.0142x over previous
//
#include <hip/hip_runtime.h>
#include <hip/hip_bf16.h>

using u16 = unsigned short;
typedef __attribute__((ext_vector_type(8))) short bf16x8;
typedef __attribute__((ext_vector_type(4))) float f32x4;
typedef __attribute__((ext_vector_type(8))) u16 u16x8;
typedef __attribute__((ext_vector_type(4))) u16 u16x4;

#define B_ 2
#define N_ 4096
#define E_ 1024
#define R_ 128
#define H_ 8
#define M_ 8192      // B*N
#define CHUNK_ 128
#define NC_ 32       // N/CHUNK
#define BH_ 16       // B*H

__device__ __forceinline__ float b2f(u16 u) { return __uint_as_float(((unsigned)u) << 16); }
__device__ __forceinline__ u16 f2b(float f) {
  unsigned u = __float_as_uint(f);
  return (u16)((u + 0x7fffu + ((u >> 16) & 1u)) >> 16);   // RNE
}
// fast sigmoid (native v_exp + v_rcp; rel err ~2^-21, fine for bf16 out)
__device__ __forceinline__ float sigm(float x) {
  return __builtin_amdgcn_rcpf(1.0f + __expf(-x));
}

#define GLDS(g, l) __builtin_amdgcn_global_load_lds( \
    (const __attribute__((address_space(1))) unsigned int*)(g), \
    (__attribute__((address_space(3))) unsigned int*)(l), 16, 0, 0)

// ---------------------------------------------------------------------------
// fp32 -> bf16 conversion (x, weights into Wcat/Wcat2/Wo, zero pad).
// ---------------------------------------------------------------------------
struct CvtArgs {
  const float* src[10];
  u16* dst[11];
};

__global__ void __launch_bounds__(256) cvt_all(CvtArgs a) {
  int idx = blockIdx.x * 256 + threadIdx.x;   // float4-granule index; grid exact
  const int SZ[11] = {2097152, 262144, 262144, 262144, 2048,
                      32768, 32768, 32768, 32768, 262144, 30720};
  int off = idx, seg = 0;
#pragma unroll
  for (int i = 0; i < 10; i++) {
    if (seg == i && off >= SZ[i]) { off -= SZ[i]; seg = i + 1; }
  }
  u16x4 z = (u16x4){0, 0, 0, 0};
  if (seg == 10) { ((u16x4*)a.dst[10])[off] = z; return; }   // Wcat pad rows
  float4 v = ((const float4*)a.src[seg])[off];
  u16x4 r;
  r[0] = f2b(v.x); r[1] = f2b(v.y); r[2] = f2b(v.z); r[3] = f2b(v.w);
  if (seg == 6) {              // Wb2 -> Wcat2 rows 0-1023, cols 0-127 (+zero cols 128-255)
    int n = off >> 5, c = off & 31;
    u16x4* W2 = (u16x4*)a.dst[6];
    W2[n * 64 + c] = r; W2[n * 64 + 32 + c] = z;
  } else if (seg == 8) {       // Wg2 -> Wcat2 rows 1024-2047, cols 128-255 (+zero cols 0-127)
    int n = off >> 5, c = off & 31;
    u16x4* W2 = (u16x4*)a.dst[8];
    W2[(1024 + n) * 64 + 32 + c] = r; W2[(1024 + n) * 64 + c] = z;
  } else {
    ((u16x4*)a.dst[seg])[off] = r;
  }
}

// ---------------------------------------------------------------------------
// BK=64 GEMM K-loop, 128x128 tile, 4 waves (kept for bg_gemm / out_gemm).
// ---------------------------------------------------------------------------
template<bool SWAP>
__device__ __forceinline__ void mfma_panel(f32x4 (&acc)[4][4], const u16* A, const u16* Bm,
                                           int wr, int wc, int l15, int q8) {
  bf16x8 af[4], bf[4];
#pragma unroll
  for (int mi = 0; mi < 4; mi++) af[mi] = *(const bf16x8*)&A[(wr * 64 + mi * 16 + l15) * 32 + q8];
#pragma unroll
  for (int ni = 0; ni < 4; ni++) bf[ni] = *(const bf16x8*)&Bm[(wc * 64 + ni * 16 + l15) * 32 + q8];
#pragma unroll
  for (int mi = 0; mi < 4; mi++)
#pragma unroll
    for (int ni = 0; ni < 4; ni++)
      acc[mi][ni] = SWAP
        ? __builtin_amdgcn_mfma_f32_16x16x32_bf16(bf[ni], af[mi], acc[mi][ni], 0, 0, 0)
        : __builtin_amdgcn_mfma_f32_16x16x32_bf16(af[mi], bf[ni], acc[mi][ni], 0, 0, 0);
}

template<bool SWAP, int K>
__device__ __forceinline__ void gemm_loop(const u16* __restrict__ X, const u16* __restrict__ W,
                                          int m0, int n0,
                                          u16* As, u16* Bs, f32x4 (&acc)[4][4], int tid) {
  const int wave = tid >> 6, lane = tid & 63;
  const int wr = wave >> 1, wc = wave & 1, l15 = lane & 15, q8 = (lane >> 4) * 8;
  const u16* Ap = X + (size_t)(m0 + wave * 32 + (lane >> 2)) * K + (lane & 3) * 8;
  const u16* Bp = W + (size_t)(n0 + wave * 32 + (lane >> 2)) * K + (lane & 3) * 8;
  u16* A0 = As + wave * 1024;
  u16* B0 = Bs + wave * 1024;
#pragma unroll
  for (int k0 = 0; k0 < K; k0 += 64) {
    GLDS(Ap + k0,                    A0);
    GLDS(Ap + 16 * (size_t)K + k0,   A0 + 512);
    GLDS(Ap + k0 + 32,               A0 + 4096);
    GLDS(Ap + 16 * (size_t)K + k0 + 32, A0 + 4608);
    GLDS(Bp + k0,                    B0);
    GLDS(Bp + 16 * (size_t)K + k0,   B0 + 512);
    GLDS(Bp + k0 + 32,               B0 + 4096);
    GLDS(Bp + 16 * (size_t)K + k0 + 32, B0 + 4608);
    __syncthreads();
    mfma_panel<SWAP>(acc, As, Bs, wr, wc, l15, q8);
    mfma_panel<SWAP>(acc, As + 4096, Bs + 4096, wr, wc, l15, q8);
    __syncthreads();
  }
}

// ---------------------------------------------------------------------------
// Mega-GEMM, 256x256 tile / BK=64 / 8 waves / 8-phase counted-vmcnt schedule.
// Round-2 fix vs round-1: fragment REUSE across phases (24 ds_read_b128 per
// wave per K-tile instead of 48) + lazy compiler-derived lgkm waits instead
// of a forced lgkmcnt(0) drain per phase. Phase order per tile:
// (MH,NH) = (0,0),(1,0),(0,1),(1,1); afr[2][4][2] + bfr[2][2] persistent.
// Reads: ph_a issues A(MH0)+B(NH0)+A(MH1) (MFMA needs only first 12; A(MH1)
// drains under MFMA); ph_b issues B(NH1) AFTER its MFMA cluster; ph_c/ph_d
// issue none. Staging positions + vmcnt(4) ledger unchanged from round 1
// (re-verified against the new read placement: every staged region's reads
// are issued >=1 phase earlier and drained >=1 barrier before GLDS issue).
// ---------------------------------------------------------------------------
__global__ void __launch_bounds__(512, 2) mega_gemm256(
    const u16* __restrict__ X, const u16* __restrict__ Wcat,
    const float* __restrict__ llb,
    u16* __restrict__ Qb, u16* __restrict__ Kb,
    u16* __restrict__ KT, u16* __restrict__ VT,
    u16* __restrict__ T1, float* __restrict__ LOGF) {
  __shared__ u16 sh[65536];          // 128 KiB
  const int tid = threadIdx.x;
  const int w = tid >> 6, lane = tid & 63;
  const int wr = w >> 2, wc = w & 3;
  const int l15 = lane & 15, g = lane >> 4;
  const int l7 = l15 & 7;

  // bijective XCD swizzle (448 % 8 == 0), nt fast within each XCD chunk
  int flat = blockIdx.x;
  int swz = (flat & 7) * 56 + (flat >> 3);
  const int nt = swz % 14, mt = swz / 14;
  const int m0 = mt * 256, n0 = nt * 256;

  u16* const A0 = sh;
  u16* const B0 = sh + 16384;
  u16* const A1 = sh + 32768;
  u16* const B1 = sh + 49152;
  u16* const bufA[2] = {A0, A1};
  u16* const bufB[2] = {B0, B1};

  // ---- staging source pointers (k=0), swizzle pre-applied to source col ----
  const int lrow = lane >> 3;                  // 0..7
  const int lcol = ((lane & 7) ^ lrow) * 8;    // u16 offset in 64-col K-tile
  const int rbA[4] = {0, 128, 64, 192};        // {Aα0,Aα1,Aβ0,Aβ1} lds rowbases
  const int rbB[4] = {0, 64, 128, 192};        // {Bα0,Bα1,Bβ0,Bβ1} lds ρ-bases
  const u16* pA[4];
  const u16* pB[4];
#pragma unroll
  for (int c = 0; c < 4; c++) {
    pA[c] = X + (size_t)(m0 + rbA[c] + w * 8 + lrow) * 1024 + lcol;
    int rho = rbB[c] + w * 8 + lrow;           // permuted B lds row
    int nh = rho >> 7, rr = rho & 127;
    int nsrc = nh * 32 + ((rr >> 5) << 6) + (rr & 31);
    pB[c] = Wcat + (size_t)(n0 + nsrc) * 1024 + lcol;
  }

  // ds_read per-thread bases (bytes)
  const int arow = (wr * 128 + l15) * 128;
  const int brow = (wc * 32 + l15) * 128;
  const int sA0 = (g ^ l7) << 4;               // ksub 0 slot (swizzled)
  const int sA1 = sA0 ^ 64;                    // ksub 1

  f32x4 acc[8][4];
#pragma unroll
  for (int i = 0; i < 8; i++)
#pragma unroll
    for (int j = 0; j < 4; j++) acc[i][j] = (f32x4){0.f, 0.f, 0.f, 0.f};

  // persistent fragment registers (all indices compile-time -> regs)
  bf16x8 afr[2][4][2];
  bf16x8 bfr[2][2];

#define SA(T, c) GLDS(pA[c] + (size_t)(T) * 64, \
    (u16*)((char*)bufA[(T) & 1] + rbA[c] * 128 + w * 1024))
#define SB(T, c) GLDS(pB[c] + (size_t)(T) * 64, \
    (u16*)((char*)bufB[(T) & 1] + rbB[c] * 128 + w * 1024))

#define RD_A(Ab, MH) {                                                          \
    const char* Abase_ = (const char*)(Ab) + arow + (MH) * 8192;                \
    _Pragma("unroll") for (int mi2 = 0; mi2 < 4; mi2++) {                       \
      afr[MH][mi2][0] = *(const bf16x8*)(Abase_ + mi2 * 2048 + sA0);            \
      afr[MH][mi2][1] = *(const bf16x8*)(Abase_ + mi2 * 2048 + sA1);            \
    } }
#define RD_B(Bb, NH) {                                                          \
    const char* Bbase_ = (const char*)(Bb) + brow + (NH) * 16384;               \
    _Pragma("unroll") for (int ni2 = 0; ni2 < 2; ni2++) {                       \
      bfr[ni2][0] = *(const bf16x8*)(Bbase_ + ni2 * 2048 + sA0);                \
      bfr[ni2][1] = *(const bf16x8*)(Bbase_ + ni2 * 2048 + sA1);                \
    } }

#define PHASE(MH, NH, READS, READS_POST, STAGES, WAITOP)                        \
  {                                                                             \
    READS;                                                                      \
    STAGES;                                                                     \
    __builtin_amdgcn_sched_barrier(0);                                          \
    __builtin_amdgcn_s_barrier();                                               \
    __builtin_amdgcn_sched_barrier(0);                                          \
    __builtin_amdgcn_s_setprio(1);                                              \
    _Pragma("unroll") for (int mi2 = 0; mi2 < 4; mi2++)                         \
      _Pragma("unroll") for (int ni2 = 0; ni2 < 2; ni2++) {                     \
        acc[(MH)*4+mi2][(NH)*2+ni2] = __builtin_amdgcn_mfma_f32_16x16x32_bf16(  \
            bfr[ni2][0], afr[MH][mi2][0], acc[(MH)*4+mi2][(NH)*2+ni2], 0, 0, 0);\
        acc[(MH)*4+mi2][(NH)*2+ni2] = __builtin_amdgcn_mfma_f32_16x16x32_bf16(  \
            bfr[ni2][1], afr[MH][mi2][1], acc[(MH)*4+mi2][(NH)*2+ni2], 0, 0, 0);\
      }                                                                         \
    __builtin_amdgcn_s_setprio(0);                                              \
    READS_POST;                                                                 \
    WAITOP;                                                                     \
    __builtin_amdgcn_sched_barrier(0);                                          \
    __builtin_amdgcn_s_barrier();                                               \
    __builtin_amdgcn_sched_barrier(0);                                          \
  }

#define NOOP ((void)0)
// vmcnt ledger identical to round 1: at ph3 the 8 loads of tile 2i+1 are the
// oldest -> vmcnt(4) certifies buf1 before ph4 reads; at ph7 the 8 loads of
// tile 2i+2 are the oldest -> vmcnt(4) certifies buf0 before next-iter ph0.
#define ITER(i, LAST)                                                           \
  PHASE(0,0, { RD_A(A0,0); RD_B(B0,0); RD_A(A0,1); }, NOOP,                     \
        { SA(2*(i)+1, 2); SA(2*(i)+1, 3); }, NOOP);                             \
  PHASE(1,0, NOOP, { RD_B(B0,1); },                                             \
        { SB(2*(i)+1, 2); SB(2*(i)+1, 3); }, NOOP);                             \
  PHASE(0,1, NOOP, NOOP,                                                        \
        { if (!(LAST)) { SA(2*(i)+2, 0); SA(2*(i)+2, 1); } }, NOOP);            \
  PHASE(1,1, NOOP, NOOP,                                                        \
        { if (!(LAST)) { SB(2*(i)+2, 0); SB(2*(i)+2, 1); } },                   \
        { if (LAST) { asm volatile("s_waitcnt vmcnt(0)" ::: "memory"); }        \
          else      { asm volatile("s_waitcnt vmcnt(4)" ::: "memory"); } });    \
  PHASE(0,0, { RD_A(A1,0); RD_B(B1,0); RD_A(A1,1); }, NOOP,                     \
        { if (!(LAST)) { SA(2*(i)+2, 2); SA(2*(i)+2, 3); } }, NOOP);            \
  PHASE(1,0, NOOP, { RD_B(B1,1); },                                             \
        { if (!(LAST)) { SB(2*(i)+2, 2); SB(2*(i)+2, 3); } }, NOOP);            \
  PHASE(0,1, NOOP, NOOP,                                                        \
        { if (!(LAST)) { SA(2*(i)+3, 0); SA(2*(i)+3, 1); } }, NOOP);            \
  PHASE(1,1, NOOP, NOOP,                                                        \
        { if (!(LAST)) { SB(2*(i)+3, 0); SB(2*(i)+3, 1); } },                   \
        { if (!(LAST)) { asm volatile("s_waitcnt vmcnt(4)" ::: "memory"); } });

  // prologue: tile 0 complete + tile 1 alpha halves; land tile 0, keep 4 in flight
  SA(0, 0); SA(0, 1); SB(0, 0); SB(0, 1);
  SA(0, 2); SA(0, 3); SB(0, 2); SB(0, 3);
  SA(1, 0); SA(1, 1); SB(1, 0); SB(1, 1);
  asm volatile("s_waitcnt vmcnt(4)" ::: "memory");
  __builtin_amdgcn_sched_barrier(0);
  __builtin_amdgcn_s_barrier();
  __builtin_amdgcn_sched_barrier(0);

#pragma unroll 1
  for (int i = 0; i < 7; ++i) {
    ITER(i, 0)
  }
  ITER(7, 1)

#undef ITER
#undef PHASE
#undef RD_A
#undef RD_B
#undef SA
#undef SB
#undef NOOP

  // ------------------------------- epilogue --------------------------------
  const int q4 = g * 4;
  const int b = m0 >> 12;
  const int nseq0 = m0 & (N_ - 1);

  if (nt < 4) {                     // Q: silu -> Qb[m][n]
#pragma unroll
    for (int mi = 0; mi < 8; mi++) {
      size_t mrow = (size_t)(m0 + wr * 128 + (mi >> 2) * 64 + (mi & 3) * 16 + l15);
#pragma unroll
      for (int ni = 0; ni < 4; ni++) {
        int nc = n0 + wc * 64 + (ni >> 1) * 32 + (ni & 1) * 16 + q4;
        u16x4 pk;
#pragma unroll
        for (int r = 0; r < 4; r++) { float v = acc[mi][ni][r]; pk[r] = f2b(v * sigm(v)); }
        *(u16x4*)&Qb[mrow * E_ + nc] = pk;
      }
    }
    return;
  }
  if (nt == 12) {                   // T1: raw
#pragma unroll
    for (int mi = 0; mi < 8; mi++) {
      size_t mrow = (size_t)(m0 + wr * 128 + (mi >> 2) * 64 + (mi & 3) * 16 + l15);
#pragma unroll
      for (int ni = 0; ni < 4; ni++) {
        int nc = n0 - 3072 + wc * 64 + (ni >> 1) * 32 + (ni & 1) * 16 + q4;
        u16x4 pk;
#pragma unroll
        for (int r = 0; r < 4; r++) pk[r] = f2b(acc[mi][ni][r]);
        *(u16x4*)&T1[mrow * 256 + nc] = pk;
      }
    }
    return;
  }
  if (nt == 13) {                   // decay logits (cols 3328-3335) -> LOGF
    if (wc == 0 && g < 2) {
#pragma unroll
      for (int mi = 0; mi < 8; mi++) {
        int nseq = nseq0 + wr * 128 + (mi >> 2) * 64 + (mi & 3) * 16 + l15;
#pragma unroll
        for (int r = 0; r < 4; r++) {
          int h = q4 + r;           // 0..7
          float lb = __expf(llb[h]);
          LOGF[(size_t)(b * H_ + h) * N_ + nseq] =
              __logf(lb + (1.f - lb) * sigm(acc[mi][0][r]));
        }
      }
    }
    return;
  }

  // K (4-7) / V (8-11): transpose 256x256 tile through LDS -> KT / VT
  const bool isK = nt < 8;
  if (isK) {                        // Kb row-major store (silu)
#pragma unroll
    for (int mi = 0; mi < 8; mi++) {
      size_t mrow = (size_t)(m0 + wr * 128 + (mi >> 2) * 64 + (mi & 3) * 16 + l15);
#pragma unroll
      for (int ni = 0; ni < 4; ni++) {
        int nc = n0 - 1024 + wc * 64 + (ni >> 1) * 32 + (ni & 1) * 16 + q4;
        u16x4 pk;
#pragma unroll
        for (int r = 0; r < 4; r++) { float v = acc[mi][ni][r]; pk[r] = f2b(v * sigm(v)); }
        *(u16x4*)&Kb[mrow * E_ + nc] = pk;
      }
    }
  }
  u16* Ts = sh;                     // [256 n][136] overlay on main LDS
  u16* DST = isK ? KT : VT;
  const int head0 = (n0 - (isK ? 1024 : 2048)) >> 7;
  __syncthreads();
#pragma unroll
  for (int pass = 0; pass < 2; pass++) {   // pass = m-half (wr)
    if (wr == pass) {
#pragma unroll
      for (int mi = 0; mi < 8; mi++) {
        int ml = (mi >> 2) * 64 + (mi & 3) * 16 + l15;  // 0..127 in this half
#pragma unroll
        for (int ni = 0; ni < 4; ni++) {
          int nl = wc * 64 + (ni >> 1) * 32 + (ni & 1) * 16 + q4;
#pragma unroll
          for (int r = 0; r < 4; r++) {
            float v = acc[mi][ni][r];
            if (isK) v = v * sigm(v);
            Ts[(nl + r) * 136 + ml] = f2b(v);
          }
        }
      }
    }
    __syncthreads();
    {
      int row = tid >> 1;                  // n-local 0..255
      int colb = (tid & 1) * 64;           // m-local base within half
      size_t drow = ((size_t)(b * H_ + head0 + (row >> 7)) * R_ + (row & 127)) * (size_t)N_;
      size_t seqb = (size_t)nseq0 + pass * 128 + colb;
#pragma unroll
      for (int j = 0; j < 8; j++) {
        u16x8 v = *(const u16x8*)&Ts[row * 136 + colb + j * 8];
        *(u16x8*)&DST[drow + seqb + j * 8] = v;
      }
    }
    if (pass == 0) __syncthreads();
  }
}

// ---------------------------------------------------------------------------
// beta+gate GEMM (swapped): T1[M,256] @ Wcat2[2048,256]^T.
// ---------------------------------------------------------------------------
__global__ void __launch_bounds__(256) bg_gemm(const u16* __restrict__ T1, const u16* __restrict__ W2,
                                               u16* __restrict__ BETA, u16* __restrict__ GATE) {
  __shared__ u16 As[8192];
  __shared__ u16 Bs[8192];
  const int tid = threadIdx.x;
  const int m0 = blockIdx.x * 128;
  const int n0 = blockIdx.y * 128;
  f32x4 acc[4][4];
#pragma unroll
  for (int i = 0; i < 4; i++)
#pragma unroll
    for (int j = 0; j < 4; j++) acc[i][j] = (f32x4){0.f, 0.f, 0.f, 0.f};
  gemm_loop<true, 256>(T1, W2, m0, n0, As, Bs, acc, tid);
  const int wave = tid >> 6, lane = tid & 63;
  const int wr = wave >> 1, wc = wave & 1, l15 = lane & 15, q4 = (lane >> 4) * 4;
#pragma unroll
  for (int mi = 0; mi < 4; mi++) {
#pragma unroll
    for (int ni = 0; ni < 4; ni++) {
      int nb = n0 + wc * 64 + ni * 16 + q4;
      int mcol = m0 + wr * 64 + mi * 16 + l15;
      u16x4 pk;
      if (nb < 1024) {
#pragma unroll
        for (int r = 0; r < 4; r++) {
          float v = acc[mi][ni][r];
          pk[r] = f2b(v * sigm(v));
        }
        *(u16x4*)&BETA[(size_t)mcol * E_ + nb] = pk;
      } else {
#pragma unroll
        for (int r = 0; r < 4; r++) pk[r] = f2b(sigm(acc[mi][ni][r]));
        *(u16x4*)&GATE[(size_t)mcol * E_ + nb - 1024] = pk;
      }
    }
  }
}

// ---------------------------------------------------------------------------
// Output GEMM (swapped): OLN[M,1024] @ Wo[1024,1024]^T -> fp32 out, float4.
// ---------------------------------------------------------------------------
__global__ void __launch_bounds__(256) out_gemm(const u16* __restrict__ X, const u16* __restrict__ W,
                                                float* __restrict__ C) {
  __shared__ u16 As[8192];
  __shared__ u16 Bs[8192];
  const int tid = threadIdx.x;
  const int m0 = blockIdx.x * 128;
  const int n0 = blockIdx.y * 128;
  f32x4 acc[4][4];
#pragma unroll
  for (int i = 0; i < 4; i++)
#pragma unroll
    for (int j = 0; j < 4; j++) acc[i][j] = (f32x4){0.f, 0.f, 0.f, 0.f};
  gemm_loop<true, 1024>(X, W, m0, n0, As, Bs, acc, tid);
  const int wave = tid >> 6, lane = tid & 63;
  const int wr = wave >> 1, wc = wave & 1, l15 = lane & 15, q4 = (lane >> 4) * 4;
#pragma unroll
  for (int mi = 0; mi < 4; mi++) {
#pragma unroll
    for (int ni = 0; ni < 4; ni++) {
      int nb = n0 + wc * 64 + ni * 16 + q4;
      int mcol = m0 + wr * 64 + mi * 16 + l15;
      *(f32x4*)&C[(size_t)mcol * E_ + nb] = acc[mi][ni];
    }
  }
}

// ---------------------------------------------------------------------------
// Householder on bf16 q (in place)
// ---------------------------------------------------------------------------
__global__ void __launch_bounds__(256) householder(u16* __restrict__ Q, const u16* __restrict__ BETA) {
  int row = blockIdx.x;
  int tid = threadIdx.x;
  u16* q = Q + (size_t)row * E_;
  const u16* bt = BETA + (size_t)row * E_;
  u16x4 q4 = *(const u16x4*)(q + tid * 4);
  u16x4 b4 = *(const u16x4*)(bt + tid * 4);
  float qv[4], bv[4];
#pragma unroll
  for (int i = 0; i < 4; i++) { qv[i] = b2f(q4[i]); bv[i] = b2f(b4[i]); }
  float ss = bv[0]*bv[0] + bv[1]*bv[1] + bv[2]*bv[2] + bv[3]*bv[3];
  float qd = qv[0]*bv[0] + qv[1]*bv[1] + qv[2]*bv[2] + qv[3]*bv[3];
  __shared__ float red[8];
#pragma unroll
  for (int m = 1; m < 64; m <<= 1) { ss += __shfl_xor(ss, m); qd += __shfl_xor(qd, m); }
  int wid = tid >> 6;
  if ((tid & 63) == 0) { red[wid] = ss; red[4 + wid] = qd; }
  __syncthreads();
  ss = red[0] + red[1] + red[2] + red[3];
  qd = red[4] + red[5] + red[6] + red[7];
  float coef = 2.f * qd / (ss + 1e-12f);
  const float scale = 0.08838834764831845f;  // 128^-0.5 folded in
  u16x4 o4;
#pragma unroll
  for (int i = 0; i < 4; i++) o4[i] = f2b((qv[i] - coef * bv[i]) * scale);
  *(u16x4*)(q + tid * 4) = o4;
}

// inclusive scan of the 128 log-decay values of one chunk into cum[] (wave 0)
__device__ __forceinline__ void scan_chunk(const float* __restrict__ lf, float* cum, int tid) {
  if (tid < 64) {
    float a = lf[tid], b = lf[tid + 64];
#pragma unroll
    for (int off = 1; off < 64; off <<= 1) {
      float t = __shfl_up(a, off);  if (tid >= off) a += t;
      float t2 = __shfl_up(b, off); if (tid >= off) b += t2;
    }
    b += __shfl(a, 63);
    cum[tid] = a; cum[tid + 64] = b;
  }
  __syncthreads();
}

// stage a [128 x 32] bf16 slab (row stride `stride` elements) into LDS [128][40]
__device__ __forceinline__ void stage32(u16* dst, const u16* src, size_t stride, int tid) {
  int r0 = tid >> 2, c8 = (tid & 3) * 8;
  *(u16x8*)&dst[(size_t)r0 * 40 + c8] = *(const u16x8*)&src[(size_t)r0 * stride + c8];
  int r1 = r0 + 64;
  *(u16x8*)&dst[(size_t)r1 * 40 + c8] = *(const u16x8*)&src[(size_t)r1 * stride + c8];
}

// same, scaling column j (slab-local) by w[j0 + j]
__device__ __forceinline__ void stage32_scaled(u16* dst, const u16* src, size_t stride,
                                               const float* w, int j0, int tid) {
  int c8 = (tid & 3) * 8;
  float wv[8];
#pragma unroll
  for (int i = 0; i < 8; i++) wv[i] = w[j0 + c8 + i];
#pragma unroll
  for (int rr = 0; rr < 128; rr += 64) {
    int r = rr + (tid >> 2);
    u16x8 raw = *(const u16x8*)&src[(size_t)r * stride + c8];
    u16x8 o;
#pragma unroll
    for (int i = 0; i < 8; i++) o[i] = f2b(b2f(raw[i]) * wv[i]);
    *(u16x8*)&dst[(size_t)r * 40 + c8] = o;
  }
}

// one K=32 MFMA step over a 128x128 output (4 waves), A/B slabs in LDS [128][40]
template<bool SWAP>
__device__ __forceinline__ void mfma16(f32x4 (&acc)[4][4], const u16* A, const u16* Bm,
                                       int wr, int wc, int l15, int q8) {
  bf16x8 af[4], bf[4];
#pragma unroll
  for (int mi = 0; mi < 4; mi++) af[mi] = *(const bf16x8*)&A[(wr * 64 + mi * 16 + l15) * 40 + q8];
#pragma unroll
  for (int ni = 0; ni < 4; ni++) bf[ni] = *(const bf16x8*)&Bm[(wc * 64 + ni * 16 + l15) * 40 + q8];
#pragma unroll
  for (int mi = 0; mi < 4; mi++)
#pragma unroll
    for (int ni = 0; ni < 4; ni++)
      acc[mi][ni] = SWAP
        ? __builtin_amdgcn_mfma_f32_16x16x32_bf16(bf[ni], af[mi], acc[mi][ni], 0, 0, 0)
        : __builtin_amdgcn_mfma_f32_16x16x32_bf16(af[mi], bf[ni], acc[mi][ni], 0, 0, 0);
}

// ---------------------------------------------------------------------------
// Phase A (MFMA, swapped): acc[mi][ni][r] = D[k = wc*64+ni*16+q4+r][v = wr*64+mi*16+l15]
// = sum_j KTw[k][j] VT[v][j]  ->  u16x4 (bf16) store at U[v][k..k+3].
// ---------------------------------------------------------------------------
__global__ void __launch_bounds__(256) gla_phaseA(const u16* __restrict__ KT, const u16* __restrict__ VT,
                                                  const float* __restrict__ LOGF,
                                                  u16* __restrict__ U, float* __restrict__ DC) {
  const int blk = blockIdx.x;
  const int bh = blk >> 5, c = blk & 31;
  const int tid = threadIdx.x;
  const int wave = tid >> 6, lane = tid & 63;
  const int wr = wave >> 1, wc = wave & 1, l15 = lane & 15, q8 = (lane >> 4) * 8;
  __shared__ u16 SA[128 * 40];
  __shared__ u16 SB[128 * 40];
  __shared__ float cum[CHUNK_];
  __shared__ float wd[CHUNK_];
  scan_chunk(LOGF + (size_t)bh * N_ + c * CHUNK_, cum, tid);
  if (tid < 128) wd[tid] = __expf(cum[127] - cum[tid]);
  __syncthreads();
  const u16* vbase = VT + ((size_t)bh * R_) * N_ + (size_t)c * CHUNK_;
  const u16* kbase = KT + ((size_t)bh * R_) * N_ + (size_t)c * CHUNK_;
  f32x4 acc[4][4];
#pragma unroll
  for (int i = 0; i < 4; i++)
#pragma unroll
    for (int j = 0; j < 4; j++) acc[i][j] = (f32x4){0.f, 0.f, 0.f, 0.f};
  for (int j0 = 0; j0 < CHUNK_; j0 += 32) {
    __syncthreads();
    stage32(SA, vbase + j0, N_, tid);
    stage32_scaled(SB, kbase + j0, N_, wd, j0, tid);
    __syncthreads();
    mfma16<true>(acc, SA, SB, wr, wc, l15, q8);
  }
  u16* Up = U + (size_t)blk * (R_ * R_);
  const int q4 = (lane >> 4) * 4;
#pragma unroll
  for (int mi = 0; mi < 4; mi++) {
#pragma unroll
    for (int ni = 0; ni < 4; ni++) {
      int v = wr * 64 + mi * 16 + l15;
      int kb = wc * 64 + ni * 16 + q4;
      u16x4 pk;
#pragma unroll
      for (int r = 0; r < 4; r++) pk[r] = f2b(acc[mi][ni][r]);
      *(u16x4*)&Up[(size_t)v * R_ + kb] = pk;
    }
  }
  if (tid == 0) DC[blk] = __expf(cum[127]);
}

// ---------------------------------------------------------------------------
// Phase B: propagate chunk-start states; U bf16 [v][k] -> SS bf16 [v][k]
// ---------------------------------------------------------------------------
__global__ void __launch_bounds__(256) gla_phaseB(const u16* __restrict__ U, const float* __restrict__ DC,
                                                  u16* __restrict__ SSb) {
  int idx = blockIdx.x * 256 + threadIdx.x;
  int bh = idx >> 14;
  int e = idx & 16383;
  float s = 0.f;
  for (int c = 0; c < NC_; c++) {
    size_t off = ((size_t)bh * NC_ + c) * 16384 + e;
    SSb[off] = f2b(s);
    s = DC[bh * NC_ + c] * s + b2f(U[off]);
  }
}

// ---------------------------------------------------------------------------
// Phase C (MFMA): o_i = exp(cum_i)*q_i@Sstart + sum_{j<=i} exp(cum_i-cum_j)(q_i.k_j) v_j
// ---------------------------------------------------------------------------
__global__ void __launch_bounds__(256) gla_phaseC(const u16* __restrict__ Qb, const u16* __restrict__ Kb,
                                                  const u16* __restrict__ VT, const u16* __restrict__ SSb,
                                                  const float* __restrict__ LOGF, u16* __restrict__ Ob) {
  const int blk = blockIdx.x;
  const int bh = blk >> 5, c = blk & 31;
  const int b = bh >> 3, h = bh & 7;
  const int tid = threadIdx.x;
  const int wave = tid >> 6, lane = tid & 63;
  const int wr = wave >> 1, wc = wave & 1, l15 = lane & 15;
  const int q4i = (lane >> 4) * 4, q8 = (lane >> 4) * 8;
  __shared__ u16 SA[128 * 40];
  __shared__ u16 SB[128 * 40];
  __shared__ u16 Ps[128 * 136];
  __shared__ float cum[CHUNK_];
  __shared__ float cumE[CHUNK_];
  scan_chunk(LOGF + (size_t)bh * N_ + c * CHUNK_, cum, tid);
  if (tid < 128) cumE[tid] = __expf(cum[tid]);
  __syncthreads();
  const size_t rowbase = ((size_t)(b * N_ + c * CHUNK_)) * E_ + (size_t)h * R_;
  const u16* vtbase = VT + ((size_t)bh * R_) * N_ + (size_t)c * CHUNK_;
  const u16* ssbase = SSb + (size_t)blk * (R_ * R_);

  f32x4 acc[4][4];
#pragma unroll
  for (int i = 0; i < 4; i++)
#pragma unroll
    for (int j = 0; j < 4; j++) acc[i][j] = (f32x4){0.f, 0.f, 0.f, 0.f};

  // ---- S^T = K @ Q^T (row=j, col=i) ----
  for (int r0 = 0; r0 < R_; r0 += 32) {
    __syncthreads();
    stage32(SA, Kb + rowbase + r0, E_, tid);   // rows j
    stage32(SB, Qb + rowbase + r0, E_, tid);   // rows i
    __syncthreads();
    mfma16<false>(acc, SA, SB, wr, wc, l15, q8);
  }
  // ---- mask + decay -> Ps[i][j] ----
#pragma unroll
  for (int mi = 0; mi < 4; mi++) {
#pragma unroll
    for (int ni = 0; ni < 4; ni++) {
      int jb = wr * 64 + mi * 16 + q4i;
      int i = wc * 64 + ni * 16 + l15;
      float ci = cum[i];
      float4 cj = *(const float4*)&cum[jb];
      u16x4 pk;
      float cjv[4] = {cj.x, cj.y, cj.z, cj.w};
#pragma unroll
      for (int r = 0; r < 4; r++) {
        int j = jb + r;
        float w = (j <= i) ? __expf(ci - cjv[r]) : 0.f;
        pk[r] = f2b(acc[mi][ni][r] * w);
      }
      *(u16x4*)&Ps[i * 136 + jb] = pk;
    }
  }
  // ---- term1 (swapped): Q @ SS^T  (row=v, col=i) ----
#pragma unroll
  for (int i = 0; i < 4; i++)
#pragma unroll
    for (int j = 0; j < 4; j++) acc[i][j] = (f32x4){0.f, 0.f, 0.f, 0.f};
  for (int k0 = 0; k0 < R_; k0 += 32) {
    __syncthreads();
    stage32(SA, Qb + rowbase + k0, E_, tid);     // rows i
    stage32(SB, ssbase + k0, R_, tid);           // rows v (SS^T layout [v][k])
    __syncthreads();
    mfma16<true>(acc, SA, SB, wr, wc, l15, q8);
  }
  // scale by exp(cum_i)
#pragma unroll
  for (int mi = 0; mi < 4; mi++) {
    float ei = cumE[wr * 64 + mi * 16 + l15];
#pragma unroll
    for (int ni = 0; ni < 4; ni++)
#pragma unroll
      for (int r = 0; r < 4; r++) acc[mi][ni][r] *= ei;
  }
  // ---- term2 (swapped): acc += P @ V^T (row=v, col=i) ----
  for (int j0 = 0; j0 < CHUNK_; j0 += 32) {
    __syncthreads();
    stage32(SB, vtbase + j0, N_, tid);           // rows v
    __syncthreads();
    if (wr == 1 || j0 < 64) {                    // wr==0 waves: i<64 -> j>=64 all masked
      bf16x8 af[4], bf[4];
#pragma unroll
      for (int mi = 0; mi < 4; mi++)
        af[mi] = *(const bf16x8*)&Ps[(wr * 64 + mi * 16 + l15) * 136 + j0 + q8];
#pragma unroll
      for (int ni = 0; ni < 4; ni++)
        bf[ni] = *(const bf16x8*)&SB[(wc * 64 + ni * 16 + l15) * 40 + q8];
#pragma unroll
      for (int mi = 0; mi < 4; mi++)
#pragma unroll
        for (int ni = 0; ni < 4; ni++)
          acc[mi][ni] = __builtin_amdgcn_mfma_f32_16x16x32_bf16(bf[ni], af[mi], acc[mi][ni], 0, 0, 0);
    }
  }
  // ---- write O (bf16, row-major [m][E]): u16x4 along v at fixed i ----
#pragma unroll
  for (int mi = 0; mi < 4; mi++) {
#pragma unroll
    for (int ni = 0; ni < 4; ni++) {
      int i = wr * 64 + mi * 16 + l15;
      int vb = wc * 64 + ni * 16 + q4i;
      u16x4 pk;
#pragma unroll
      for (int r = 0; r < 4; r++) pk[r] = f2b(acc[mi][ni][r]);
      *(u16x4*)&Ob[rowbase + (size_t)i * E_ + vb] = pk;
    }
  }
}

// ---------------------------------------------------------------------------
// o = o * gate (both bf16); LayerNorm(weight-only, fp32 gamma) -> bf16
// ---------------------------------------------------------------------------
__global__ void __launch_bounds__(256) gate_ln(const u16* __restrict__ O, const u16* __restrict__ G,
                                               const float* __restrict__ gamma, u16* __restrict__ OLN) {
  int row = blockIdx.x, tid = threadIdx.x;
  u16x4 o4 = *(const u16x4*)(O + (size_t)row * E_ + tid * 4);
  u16x4 g4 = *(const u16x4*)(G + (size_t)row * E_ + tid * 4);
  float x0 = b2f(o4[0]) * b2f(g4[0]), x1 = b2f(o4[1]) * b2f(g4[1]);
  float x2 = b2f(o4[2]) * b2f(g4[2]), x3 = b2f(o4[3]) * b2f(g4[3]);
  float s = x0 + x1 + x2 + x3;
  float sq = x0 * x0 + x1 * x1 + x2 * x2 + x3 * x3;
  __shared__ float red[8];
#pragma unroll
  for (int m = 1; m < 64; m <<= 1) { s += __shfl_xor(s, m); sq += __shfl_xor(sq, m); }
  int wid = tid >> 6;
  if ((tid & 63) == 0) { red[wid] = s; red[4 + wid] = sq; }
  __syncthreads();
  s = red[0] + red[1] + red[2] + red[3];
  sq = red[4] + red[5] + red[6] + red[7];
  float mu = s * (1.f / 1024.f);
  float var = sq * (1.f / 1024.f) - mu * mu;
  float rs = rsqrtf(var + 1e-5f);
  int e = tid * 4;
  u16x4 r4;
  r4[0] = f2b((x0 - mu) * rs * gamma[e + 0]);
  r4[1] = f2b((x1 - mu) * rs * gamma[e + 1]);
  r4[2] = f2b((x2 - mu) * rs * gamma[e + 2]);
  r4[3] = f2b((x3 - mu) * rs * gamma[e + 3]);
  *(u16x4*)(OLN + (size_t)row * E_ + e) = r4;
}

// ---------------------------------------------------------------------------
extern "C" void kernel_launch(void* const* d_in, const int* in_sizes, int n_in,
                              void* d_out, int out_size, void* d_ws, size_t ws_size,
                              hipStream_t stream) {
  (void)in_sizes; (void)n_in; (void)out_size; (void)ws_size;
  const float* x   = (const float*)d_in[0];
  const float* llb = (const float*)d_in[1];
  const float* Wq  = (const float*)d_in[2];
  const float* Wk  = (const float*)d_in[3];
  const float* Wv  = (const float*)d_in[4];
  const float* Wf  = (const float*)d_in[5];
  const float* Wb1 = (const float*)d_in[6];
  const float* Wb2 = (const float*)d_in[7];
  const float* Wg1 = (const float*)d_in[8];
  const float* Wg2 = (const float*)d_in[9];
  const float* gm  = (const float*)d_in[10];
  const float* Wo  = (const float*)d_in[11];
  float* out = (float*)d_out;

  char* ws = (char*)d_ws;
  const size_t SZB = (size_t)M_ * E_ * 2;            // 16.78 MB bf16 [M,E]
  u16*   Qb    = (u16*)(ws + 0 * SZB);               // q bf16 (OLN overlay later)
  u16*   Kb    = (u16*)(ws + 1 * SZB);
  u16*   KT    = (u16*)(ws + 2 * SZB);               // [B,H,R,N]
  u16*   VT    = (u16*)(ws + 3 * SZB);               // [B,H,R,N]
  u16*   BETAb = (u16*)(ws + 4 * SZB);               // beta -> O overlay
  u16*   GATEb = (u16*)(ws + 5 * SZB);
  u16*   SSb   = (u16*)(ws + 6 * SZB);               // chunk-start states bf16 [v][k]
  u16*   XB    = (u16*)(ws + 7 * SZB);
  u16*   U     = (u16*)(ws + 8 * SZB);               // bf16 [512][128][128]
  char*  tail  = ws + 8 * SZB + (size_t)BH_ * NC_ * R_ * R_ * 2;
  u16*   Wcat  = (u16*)tail;                         // [3456][1024]
  u16*   Wcat2 = Wcat + (size_t)3456 * 1024;         // [2048][256]
  u16*   WOb   = Wcat2 + (size_t)2048 * 256;         // [1024][1024]
  u16*   T1    = WOb + (size_t)E_ * E_;              // [M,256]
  float* LOGF  = (float*)(T1 + (size_t)M_ * 256);
  float* DC    = LOGF + (size_t)BH_ * N_;
  u16*   Ob    = BETAb;                              // overlay (beta dead after householder)
  u16*   OLN   = Qb;                                 // overlay (q dead after phaseC)

  CvtArgs ca;
  ca.src[0] = x;   ca.dst[0]  = XB;
  ca.src[1] = Wq;  ca.dst[1]  = Wcat;
  ca.src[2] = Wk;  ca.dst[2]  = Wcat + (size_t)1024 * 1024;
  ca.src[3] = Wv;  ca.dst[3]  = Wcat + (size_t)2048 * 1024;
  ca.src[4] = Wf;  ca.dst[4]  = Wcat + (size_t)3328 * 1024;
  ca.src[5] = Wb1; ca.dst[5]  = Wcat + (size_t)3072 * 1024;
  ca.src[6] = Wb2; ca.dst[6]  = Wcat2;
  ca.src[7] = Wg1; ca.dst[7]  = Wcat + (size_t)3200 * 1024;
  ca.src[8] = Wg2; ca.dst[8]  = Wcat2;
  ca.src[9] = Wo;  ca.dst[9]  = WOb;
  ca.dst[10] = Wcat + (size_t)3336 * 1024;           // zero pad rows

  dim3 blk(256);
  cvt_all<<<dim3(12928), blk, 0, stream>>>(ca);
  mega_gemm256<<<dim3(448), dim3(512), 0, stream>>>(XB, Wcat, llb, Qb, Kb, KT, VT, T1, LOGF);
  bg_gemm<<<dim3(64, 16), blk, 0, stream>>>(T1, Wcat2, BETAb, GATEb);
  householder<<<dim3(M_), blk, 0, stream>>>(Qb, BETAb);
  gla_phaseA<<<dim3(BH_ * NC_), blk, 0, stream>>>(KT, VT, LOGF, U, DC);
  gla_phaseB<<<dim3(BH_ * 16384 / 256), blk, 0, stream>>>(U, DC, SSb);
  gla_phaseC<<<dim3(BH_ * NC_), blk, 0, stream>>>(Qb, Kb, VT, SSb, LOGF, Ob);
  gate_ln<<<dim3(M_), blk, 0, stream>>>(Ob, GATEb, gm, OLN);
  out_gemm<<<dim3(64, 8), blk, 0, stream>>>(OLN, WOb, out);
}

// Round 4
// 310.091 us; speedup vs baseline: 1.0267x; 1.0123x over previous
//
#include <hip/hip_runtime.h>
#include <hip/hip_bf16.h>

using u16 = unsigned short;
typedef __attribute__((ext_vector_type(8))) short bf16x8;
typedef __attribute__((ext_vector_type(4))) float f32x4;
typedef __attribute__((ext_vector_type(8))) u16 u16x8;
typedef __attribute__((ext_vector_type(4))) u16 u16x4;

#define B_ 2
#define N_ 4096
#define E_ 1024
#define R_ 128
#define H_ 8
#define M_ 8192      // B*N
#define CHUNK_ 128
#define NC_ 32       // N/CHUNK
#define BH_ 16       // B*H

__device__ __forceinline__ float b2f(u16 u) { return __uint_as_float(((unsigned)u) << 16); }
__device__ __forceinline__ u16 f2b(float f) {
  unsigned u = __float_as_uint(f);
  return (u16)((u + 0x7fffu + ((u >> 16) & 1u)) >> 16);   // RNE
}
// fast sigmoid (native v_exp + v_rcp; rel err ~2^-21, fine for bf16 out)
__device__ __forceinline__ float sigm(float x) {
  return __builtin_amdgcn_rcpf(1.0f + __expf(-x));
}

#define GLDS(g, l) __builtin_amdgcn_global_load_lds( \
    (const __attribute__((address_space(1))) unsigned int*)(g), \
    (__attribute__((address_space(3))) unsigned int*)(l), 16, 0, 0)

// ---------------------------------------------------------------------------
// fp32 -> bf16 conversion (x, weights into Wcat/Wcat2/Wo, zero pad).
// ---------------------------------------------------------------------------
struct CvtArgs {
  const float* src[10];
  u16* dst[11];
};

__global__ void __launch_bounds__(256) cvt_all(CvtArgs a) {
  int idx = blockIdx.x * 256 + threadIdx.x;   // float4-granule index; grid exact
  const int SZ[11] = {2097152, 262144, 262144, 262144, 2048,
                      32768, 32768, 32768, 32768, 262144, 30720};
  int off = idx, seg = 0;
#pragma unroll
  for (int i = 0; i < 10; i++) {
    if (seg == i && off >= SZ[i]) { off -= SZ[i]; seg = i + 1; }
  }
  u16x4 z = (u16x4){0, 0, 0, 0};
  if (seg == 10) { ((u16x4*)a.dst[10])[off] = z; return; }   // Wcat pad rows
  float4 v = ((const float4*)a.src[seg])[off];
  u16x4 r;
  r[0] = f2b(v.x); r[1] = f2b(v.y); r[2] = f2b(v.z); r[3] = f2b(v.w);
  if (seg == 6) {              // Wb2 -> Wcat2 rows 0-1023, cols 0-127 (+zero cols 128-255)
    int n = off >> 5, c = off & 31;
    u16x4* W2 = (u16x4*)a.dst[6];
    W2[n * 64 + c] = r; W2[n * 64 + 32 + c] = z;
  } else if (seg == 8) {       // Wg2 -> Wcat2 rows 1024-2047, cols 128-255 (+zero cols 0-127)
    int n = off >> 5, c = off & 31;
    u16x4* W2 = (u16x4*)a.dst[8];
    W2[(1024 + n) * 64 + 32 + c] = r; W2[(1024 + n) * 64 + c] = z;
  } else {
    ((u16x4*)a.dst[seg])[off] = r;
  }
}

// ---------------------------------------------------------------------------
// BK=64 GEMM K-loop, 128x128 tile, 4 waves (kept for bg_gemm / out_gemm).
// ---------------------------------------------------------------------------
template<bool SWAP>
__device__ __forceinline__ void mfma_panel(f32x4 (&acc)[4][4], const u16* A, const u16* Bm,
                                           int wr, int wc, int l15, int q8) {
  bf16x8 af[4], bf[4];
#pragma unroll
  for (int mi = 0; mi < 4; mi++) af[mi] = *(const bf16x8*)&A[(wr * 64 + mi * 16 + l15) * 32 + q8];
#pragma unroll
  for (int ni = 0; ni < 4; ni++) bf[ni] = *(const bf16x8*)&Bm[(wc * 64 + ni * 16 + l15) * 32 + q8];
#pragma unroll
  for (int mi = 0; mi < 4; mi++)
#pragma unroll
    for (int ni = 0; ni < 4; ni++)
      acc[mi][ni] = SWAP
        ? __builtin_amdgcn_mfma_f32_16x16x32_bf16(bf[ni], af[mi], acc[mi][ni], 0, 0, 0)
        : __builtin_amdgcn_mfma_f32_16x16x32_bf16(af[mi], bf[ni], acc[mi][ni], 0, 0, 0);
}

template<bool SWAP, int K>
__device__ __forceinline__ void gemm_loop(const u16* __restrict__ X, const u16* __restrict__ W,
                                          int m0, int n0,
                                          u16* As, u16* Bs, f32x4 (&acc)[4][4], int tid) {
  const int wave = tid >> 6, lane = tid & 63;
  const int wr = wave >> 1, wc = wave & 1, l15 = lane & 15, q8 = (lane >> 4) * 8;
  const u16* Ap = X + (size_t)(m0 + wave * 32 + (lane >> 2)) * K + (lane & 3) * 8;
  const u16* Bp = W + (size_t)(n0 + wave * 32 + (lane >> 2)) * K + (lane & 3) * 8;
  u16* A0 = As + wave * 1024;
  u16* B0 = Bs + wave * 1024;
#pragma unroll
  for (int k0 = 0; k0 < K; k0 += 64) {
    GLDS(Ap + k0,                    A0);
    GLDS(Ap + 16 * (size_t)K + k0,   A0 + 512);
    GLDS(Ap + k0 + 32,               A0 + 4096);
    GLDS(Ap + 16 * (size_t)K + k0 + 32, A0 + 4608);
    GLDS(Bp + k0,                    B0);
    GLDS(Bp + 16 * (size_t)K + k0,   B0 + 512);
    GLDS(Bp + k0 + 32,               B0 + 4096);
    GLDS(Bp + 16 * (size_t)K + k0 + 32, B0 + 4608);
    __syncthreads();
    mfma_panel<SWAP>(acc, As, Bs, wr, wc, l15, q8);
    mfma_panel<SWAP>(acc, As + 4096, Bs + 4096, wr, wc, l15, q8);
    __syncthreads();
  }
}

// ---------------------------------------------------------------------------
// NEW K-loop for mega_gemm: 128x128 tile / BK=32 double-buffered stage-ahead,
// 4 waves, K=1024, one __syncthreads per K-tile (implicit vmcnt/lgkm drain is
// the full dbuf ledger). 16-B slot swizzle slot = g ^ ((row ^ row>>2)&3),
// applied to the GLOBAL source col (GLDS dest linear) and the ds_read slot
// (same involution both sides) -> 2-way (free) bank access instead of 8-way.
// LDS byte layout in sh: A0 @0, B0 @8192, A1 @16384, B1 @24576 (32 KB used).
// acc mapping identical to round-0 gemm_loop:
//   SWAP:  acc[mi][ni][r] = C[m0+wr*64+mi*16+l15][n0+wc*64+ni*16+q4+r]
//   !SWAP: acc[mi][ni][r] = C[m0+wr*64+mi*16+q4+r][n0+wc*64+ni*16+l15]
// ---------------------------------------------------------------------------
template<bool SWAP>
__device__ __forceinline__ void gemm128_dbuf(const u16* __restrict__ X, const u16* __restrict__ W,
                                             int m0, int n0, u16* sh, f32x4 (&acc)[4][4], int tid) {
  const int w = tid >> 6, lane = tid & 63;
  const int wr = w >> 1, wc = w & 1;
  const int l15 = lane & 15, g = lane >> 4;
  const int lrow = tid >> 2;                                  // 0..63
  const int scol = (tid & 3) ^ ((lrow ^ (lrow >> 2)) & 3);    // pre-swizzled src slot
  const u16* pA0 = X + (size_t)(m0 + lrow) * 1024 + scol * 8;
  const u16* pA1 = X + (size_t)(m0 + 64 + lrow) * 1024 + scol * 8;
  const u16* pB0 = W + (size_t)(n0 + lrow) * 1024 + scol * 8;
  const u16* pB1 = W + (size_t)(n0 + 64 + lrow) * 1024 + scol * 8;
  const int sw = (g ^ (l15 & 3) ^ ((l15 >> 2) & 3)) << 4;     // swizzled read slot (bytes)
  const int abase = (wr * 64 + l15) * 64 + sw;                // bytes into A buf
  const int bbase = (wc * 64 + l15) * 64 + sw;                // bytes into B buf

#define STG128(T, bi) do {                                                      \
    char* Ad_ = (char*)sh + (bi) * 16384;                                       \
    char* Bd_ = (char*)sh + 8192 + (bi) * 16384;                                \
    GLDS(pA0 + (size_t)(T) * 32, Ad_ + w * 1024);                               \
    GLDS(pA1 + (size_t)(T) * 32, Ad_ + 4096 + w * 1024);                        \
    GLDS(pB0 + (size_t)(T) * 32, Bd_ + w * 1024);                               \
    GLDS(pB1 + (size_t)(T) * 32, Bd_ + 4096 + w * 1024);                        \
  } while (0)

  STG128(0, 0);
  __syncthreads();                   // implicit vmcnt(0): tile 0 landed

#pragma unroll 2
  for (int t = 0; t < 32; ++t) {
    if (t < 31) STG128(t + 1, (t + 1) & 1);
    const char* Ab = (const char*)sh + (t & 1) * 16384;
    const char* Bb = (const char*)sh + 8192 + (t & 1) * 16384;
    bf16x8 af[4], bf[4];
#pragma unroll
    for (int mi = 0; mi < 4; mi++) af[mi] = *(const bf16x8*)(Ab + abase + mi * 1024);
#pragma unroll
    for (int ni = 0; ni < 4; ni++) bf[ni] = *(const bf16x8*)(Bb + bbase + ni * 1024);
    __builtin_amdgcn_s_setprio(1);
#pragma unroll
    for (int mi = 0; mi < 4; mi++)
#pragma unroll
      for (int ni = 0; ni < 4; ni++)
        acc[mi][ni] = SWAP
          ? __builtin_amdgcn_mfma_f32_16x16x32_bf16(bf[ni], af[mi], acc[mi][ni], 0, 0, 0)
          : __builtin_amdgcn_mfma_f32_16x16x32_bf16(af[mi], bf[ni], acc[mi][ni], 0, 0, 0);
    __builtin_amdgcn_s_setprio(0);
    __syncthreads();                 // drains stage of t+1 + protects dbuf swap
  }
#undef STG128
}

// ---------------------------------------------------------------------------
// Mega-GEMM: X[M,1024] @ Wcat[3456,1024]^T. Grid (27, 64): x = ny (so
// concurrent blocks share Wcat columns in L2), y = m-tile.
//  ny 0-7   (swapped): silu -> Qb u16x4
//  ny 8-15  (swapped): silu -> Kb u16x4 + KT via LDS scalar-transpose
//  ny 16-23 (unswapped): -> VT direct u16x4 (C/D rows run along m = seq dim)
//  ny 24-25 (swapped): -> T1 u16x4
//  ny 26    (swapped): f logits -> LOGF
// ---------------------------------------------------------------------------
__global__ void __launch_bounds__(256, 4) mega_gemm(const u16* __restrict__ X, const u16* __restrict__ Wcat,
                                                    const float* __restrict__ llb,
                                                    u16* __restrict__ Qb, u16* __restrict__ Kb,
                                                    u16* __restrict__ KT, u16* __restrict__ VT,
                                                    u16* __restrict__ T1, float* __restrict__ LOGF) {
  __shared__ u16 sh[17408];           // K-loop uses first 32 KB; Ts overlays (stride 136)
  u16* Ts = sh;
  const int tid = threadIdx.x;
  const int m0 = blockIdx.y * 128;
  const int ny = blockIdx.x, n0 = ny * 128;
  const int wave = tid >> 6, lane = tid & 63;
  const int wr = wave >> 1, wc = wave & 1, l15 = lane & 15, q4 = (lane >> 4) * 4;
  f32x4 acc[4][4];
#pragma unroll
  for (int i = 0; i < 4; i++)
#pragma unroll
    for (int j = 0; j < 4; j++) acc[i][j] = (f32x4){0.f, 0.f, 0.f, 0.f};

  if (ny >= 16 && ny < 24) {
    // ---- V block: unswapped -> rows (q4+r) = m-dim -> direct u16x4 into VT ----
    gemm128_dbuf<false>(X, Wcat, m0, n0, sh, acc, tid);
#pragma unroll
    for (int mi = 0; mi < 4; mi++) {
#pragma unroll
      for (int ni = 0; ni < 4; ni++) {
        int col = n0 - 2048 + wc * 64 + ni * 16 + l15;   // v-dim 0..1023
        int rbase = m0 + wr * 64 + mi * 16 + q4;         // m-dim (4 consecutive)
        int head = col >> 7, rl = col & 127;
        int bb = rbase >> 12, nseq = rbase & (N_ - 1);
        u16x4 pk;
#pragma unroll
        for (int r = 0; r < 4; r++) pk[r] = f2b(acc[mi][ni][r]);
        *(u16x4*)&VT[((size_t)(bb * H_ + head) * R_ + rl) * N_ + nseq] = pk;
      }
    }
    return;
  }

  gemm128_dbuf<true>(X, Wcat, m0, n0, sh, acc, tid);

  if (ny == 26) {                     // decay logits -> LOGF
    // n-local = wc*64 + ni*16 + q4 + r < 8  =>  wc==0, ni==0, q4 in {0,4}
    if (wc == 0 && (lane >> 4) < 2) {
#pragma unroll
      for (int mi = 0; mi < 4; mi++) {
        int mcol = m0 + wr * 64 + mi * 16 + l15;
        int bb = mcol >> 12, nseq = mcol & (N_ - 1);
#pragma unroll
        for (int r = 0; r < 4; r++) {
          int h = q4 + r;             // 0..7
          float lb = __expf(llb[h]);
          LOGF[(size_t)(bb * H_ + h) * N_ + nseq] =
              __logf(lb + (1.f - lb) * sigm(acc[mi][0][r]));
        }
      }
    }
    return;
  }

  // swapped: lane holds 4 consecutive n (nb..nb+3) at fixed m (mcol)
#pragma unroll
  for (int mi = 0; mi < 4; mi++) {
#pragma unroll
    for (int ni = 0; ni < 4; ni++) {
      int nb = n0 + wc * 64 + ni * 16 + q4;
      int mcol = m0 + wr * 64 + mi * 16 + l15;
      u16x4 pk;
#pragma unroll
      for (int r = 0; r < 4; r++) {
        float v = acc[mi][ni][r];
        if (ny < 16) v = v * sigm(v);
        pk[r] = f2b(v);
      }
      if (ny < 8) {
        *(u16x4*)&Qb[(size_t)mcol * E_ + nb] = pk;
      } else if (ny < 16) {
        *(u16x4*)&Kb[(size_t)mcol * E_ + nb - 1024] = pk;
        int nl = nb - n0;             // local k-dim 0..127
        int ml = mcol - m0;           // local m 0..127
#pragma unroll
        for (int r = 0; r < 4; r++) Ts[(nl + r) * 136 + ml] = pk[r];
      } else {                        // ny 24/25 -> T1
        *(u16x4*)&T1[(size_t)mcol * 256 + nb - 3072] = pk;
      }
    }
  }

  if (ny >= 8 && ny < 16) {           // KT copy-out from Ts[nl][ml]
    __syncthreads();
    int head = (n0 - 1024) >> 7;
    int bb = m0 >> 12, nloc = m0 & (N_ - 1);
    size_t base = ((size_t)(bb * H_ + head) * R_) * N_ + nloc;
#pragma unroll
    for (int p = 0; p < 8; p++) {
      int nl = p * 16 + (tid >> 4);
      int m8 = (tid & 15) * 8;
      u16x8 v = *(const u16x8*)&Ts[nl * 136 + m8];
      *(u16x8*)&KT[base + (size_t)nl * N_ + m8] = v;
    }
  }
}

// ---------------------------------------------------------------------------
// beta+gate GEMM (swapped): T1[M,256] @ Wcat2[2048,256]^T.
// ---------------------------------------------------------------------------
__global__ void __launch_bounds__(256) bg_gemm(const u16* __restrict__ T1, const u16* __restrict__ W2,
                                               u16* __restrict__ BETA, u16* __restrict__ GATE) {
  __shared__ u16 As[8192];
  __shared__ u16 Bs[8192];
  const int tid = threadIdx.x;
  const int m0 = blockIdx.x * 128;
  const int n0 = blockIdx.y * 128;
  f32x4 acc[4][4];
#pragma unroll
  for (int i = 0; i < 4; i++)
#pragma unroll
    for (int j = 0; j < 4; j++) acc[i][j] = (f32x4){0.f, 0.f, 0.f, 0.f};
  gemm_loop<true, 256>(T1, W2, m0, n0, As, Bs, acc, tid);
  const int wave = tid >> 6, lane = tid & 63;
  const int wr = wave >> 1, wc = wave & 1, l15 = lane & 15, q4 = (lane >> 4) * 4;
#pragma unroll
  for (int mi = 0; mi < 4; mi++) {
#pragma unroll
    for (int ni = 0; ni < 4; ni++) {
      int nb = n0 + wc * 64 + ni * 16 + q4;
      int mcol = m0 + wr * 64 + mi * 16 + l15;
      u16x4 pk;
      if (nb < 1024) {
#pragma unroll
        for (int r = 0; r < 4; r++) {
          float v = acc[mi][ni][r];
          pk[r] = f2b(v * sigm(v));
        }
        *(u16x4*)&BETA[(size_t)mcol * E_ + nb] = pk;
      } else {
#pragma unroll
        for (int r = 0; r < 4; r++) pk[r] = f2b(sigm(acc[mi][ni][r]));
        *(u16x4*)&GATE[(size_t)mcol * E_ + nb - 1024] = pk;
      }
    }
  }
}

// ---------------------------------------------------------------------------
// Output GEMM (swapped): OLN[M,1024] @ Wo[1024,1024]^T -> fp32 out, float4.
// ---------------------------------------------------------------------------
__global__ void __launch_bounds__(256) out_gemm(const u16* __restrict__ X, const u16* __restrict__ W,
                                                float* __restrict__ C) {
  __shared__ u16 As[8192];
  __shared__ u16 Bs[8192];
  const int tid = threadIdx.x;
  const int m0 = blockIdx.x * 128;
  const int n0 = blockIdx.y * 128;
  f32x4 acc[4][4];
#pragma unroll
  for (int i = 0; i < 4; i++)
#pragma unroll
    for (int j = 0; j < 4; j++) acc[i][j] = (f32x4){0.f, 0.f, 0.f, 0.f};
  gemm_loop<true, 1024>(X, W, m0, n0, As, Bs, acc, tid);
  const int wave = tid >> 6, lane = tid & 63;
  const int wr = wave >> 1, wc = wave & 1, l15 = lane & 15, q4 = (lane >> 4) * 4;
#pragma unroll
  for (int mi = 0; mi < 4; mi++) {
#pragma unroll
    for (int ni = 0; ni < 4; ni++) {
      int nb = n0 + wc * 64 + ni * 16 + q4;
      int mcol = m0 + wr * 64 + mi * 16 + l15;
      *(f32x4*)&C[(size_t)mcol * E_ + nb] = acc[mi][ni];
    }
  }
}

// ---------------------------------------------------------------------------
// Householder on bf16 q (in place)
// ---------------------------------------------------------------------------
__global__ void __launch_bounds__(256) householder(u16* __restrict__ Q, const u16* __restrict__ BETA) {
  int row = blockIdx.x;
  int tid = threadIdx.x;
  u16* q = Q + (size_t)row * E_;
  const u16* bt = BETA + (size_t)row * E_;
  u16x4 q4 = *(const u16x4*)(q + tid * 4);
  u16x4 b4 = *(const u16x4*)(bt + tid * 4);
  float qv[4], bv[4];
#pragma unroll
  for (int i = 0; i < 4; i++) { qv[i] = b2f(q4[i]); bv[i] = b2f(b4[i]); }
  float ss = bv[0]*bv[0] + bv[1]*bv[1] + bv[2]*bv[2] + bv[3]*bv[3];
  float qd = qv[0]*bv[0] + qv[1]*bv[1] + qv[2]*bv[2] + qv[3]*bv[3];
  __shared__ float red[8];
#pragma unroll
  for (int m = 1; m < 64; m <<= 1) { ss += __shfl_xor(ss, m); qd += __shfl_xor(qd, m); }
  int wid = tid >> 6;
  if ((tid & 63) == 0) { red[wid] = ss; red[4 + wid] = qd; }
  __syncthreads();
  ss = red[0] + red[1] + red[2] + red[3];
  qd = red[4] + red[5] + red[6] + red[7];
  float coef = 2.f * qd / (ss + 1e-12f);
  const float scale = 0.08838834764831845f;  // 128^-0.5 folded in
  u16x4 o4;
#pragma unroll
  for (int i = 0; i < 4; i++) o4[i] = f2b((qv[i] - coef * bv[i]) * scale);
  *(u16x4*)(q + tid * 4) = o4;
}

// inclusive scan of the 128 log-decay values of one chunk into cum[] (wave 0)
__device__ __forceinline__ void scan_chunk(const float* __restrict__ lf, float* cum, int tid) {
  if (tid < 64) {
    float a = lf[tid], b = lf[tid + 64];
#pragma unroll
    for (int off = 1; off < 64; off <<= 1) {
      float t = __shfl_up(a, off);  if (tid >= off) a += t;
      float t2 = __shfl_up(b, off); if (tid >= off) b += t2;
    }
    b += __shfl(a, 63);
    cum[tid] = a; cum[tid + 64] = b;
  }
  __syncthreads();
}

// stage a [128 x 32] bf16 slab (row stride `stride` elements) into LDS [128][40]
__device__ __forceinline__ void stage32(u16* dst, const u16* src, size_t stride, int tid) {
  int r0 = tid >> 2, c8 = (tid & 3) * 8;
  *(u16x8*)&dst[(size_t)r0 * 40 + c8] = *(const u16x8*)&src[(size_t)r0 * stride + c8];
  int r1 = r0 + 64;
  *(u16x8*)&dst[(size_t)r1 * 40 + c8] = *(const u16x8*)&src[(size_t)r1 * stride + c8];
}

// same, scaling column j (slab-local) by w[j0 + j]
__device__ __forceinline__ void stage32_scaled(u16* dst, const u16* src, size_t stride,
                                               const float* w, int j0, int tid) {
  int c8 = (tid & 3) * 8;
  float wv[8];
#pragma unroll
  for (int i = 0; i < 8; i++) wv[i] = w[j0 + c8 + i];
#pragma unroll
  for (int rr = 0; rr < 128; rr += 64) {
    int r = rr + (tid >> 2);
    u16x8 raw = *(const u16x8*)&src[(size_t)r * stride + c8];
    u16x8 o;
#pragma unroll
    for (int i = 0; i < 8; i++) o[i] = f2b(b2f(raw[i]) * wv[i]);
    *(u16x8*)&dst[(size_t)r * 40 + c8] = o;
  }
}

// one K=32 MFMA step over a 128x128 output (4 waves), A/B slabs in LDS [128][40]
template<bool SWAP>
__device__ __forceinline__ void mfma16(f32x4 (&acc)[4][4], const u16* A, const u16* Bm,
                                       int wr, int wc, int l15, int q8) {
  bf16x8 af[4], bf[4];
#pragma unroll
  for (int mi = 0; mi < 4; mi++) af[mi] = *(const bf16x8*)&A[(wr * 64 + mi * 16 + l15) * 40 + q8];
#pragma unroll
  for (int ni = 0; ni < 4; ni++) bf[ni] = *(const bf16x8*)&Bm[(wc * 64 + ni * 16 + l15) * 40 + q8];
#pragma unroll
  for (int mi = 0; mi < 4; mi++)
#pragma unroll
    for (int ni = 0; ni < 4; ni++)
      acc[mi][ni] = SWAP
        ? __builtin_amdgcn_mfma_f32_16x16x32_bf16(bf[ni], af[mi], acc[mi][ni], 0, 0, 0)
        : __builtin_amdgcn_mfma_f32_16x16x32_bf16(af[mi], bf[ni], acc[mi][ni], 0, 0, 0);
}

// ---------------------------------------------------------------------------
// Phase A (MFMA, swapped): acc[mi][ni][r] = D[k = wc*64+ni*16+q4+r][v = wr*64+mi*16+l15]
// = sum_j KTw[k][j] VT[v][j]  ->  u16x4 (bf16) store at U[v][k..k+3].
// ---------------------------------------------------------------------------
__global__ void __launch_bounds__(256) gla_phaseA(const u16* __restrict__ KT, const u16* __restrict__ VT,
                                                  const float* __restrict__ LOGF,
                                                  u16* __restrict__ U, float* __restrict__ DC) {
  const int blk = blockIdx.x;
  const int bh = blk >> 5, c = blk & 31;
  const int tid = threadIdx.x;
  const int wave = tid >> 6, lane = tid & 63;
  const int wr = wave >> 1, wc = wave & 1, l15 = lane & 15, q8 = (lane >> 4) * 8;
  __shared__ u16 SA[128 * 40];
  __shared__ u16 SB[128 * 40];
  __shared__ float cum[CHUNK_];
  __shared__ float wd[CHUNK_];
  scan_chunk(LOGF + (size_t)bh * N_ + c * CHUNK_, cum, tid);
  if (tid < 128) wd[tid] = __expf(cum[127] - cum[tid]);
  __syncthreads();
  const u16* vbase = VT + ((size_t)bh * R_) * N_ + (size_t)c * CHUNK_;
  const u16* kbase = KT + ((size_t)bh * R_) * N_ + (size_t)c * CHUNK_;
  f32x4 acc[4][4];
#pragma unroll
  for (int i = 0; i < 4; i++)
#pragma unroll
    for (int j = 0; j < 4; j++) acc[i][j] = (f32x4){0.f, 0.f, 0.f, 0.f};
  for (int j0 = 0; j0 < CHUNK_; j0 += 32) {
    __syncthreads();
    stage32(SA, vbase + j0, N_, tid);
    stage32_scaled(SB, kbase + j0, N_, wd, j0, tid);
    __syncthreads();
    mfma16<true>(acc, SA, SB, wr, wc, l15, q8);
  }
  u16* Up = U + (size_t)blk * (R_ * R_);
  const int q4 = (lane >> 4) * 4;
#pragma unroll
  for (int mi = 0; mi < 4; mi++) {
#pragma unroll
    for (int ni = 0; ni < 4; ni++) {
      int v = wr * 64 + mi * 16 + l15;
      int kb = wc * 64 + ni * 16 + q4;
      u16x4 pk;
#pragma unroll
      for (int r = 0; r < 4; r++) pk[r] = f2b(acc[mi][ni][r]);
      *(u16x4*)&Up[(size_t)v * R_ + kb] = pk;
    }
  }
  if (tid == 0) DC[blk] = __expf(cum[127]);
}

// ---------------------------------------------------------------------------
// Phase B: propagate chunk-start states; U bf16 [v][k] -> SS bf16 [v][k]
// ---------------------------------------------------------------------------
__global__ void __launch_bounds__(256) gla_phaseB(const u16* __restrict__ U, const float* __restrict__ DC,
                                                  u16* __restrict__ SSb) {
  int idx = blockIdx.x * 256 + threadIdx.x;
  int bh = idx >> 14;
  int e = idx & 16383;
  float s = 0.f;
  for (int c = 0; c < NC_; c++) {
    size_t off = ((size_t)bh * NC_ + c) * 16384 + e;
    SSb[off] = f2b(s);
    s = DC[bh * NC_ + c] * s + b2f(U[off]);
  }
}

// ---------------------------------------------------------------------------
// Phase C (MFMA): o_i = exp(cum_i)*q_i@Sstart + sum_{j<=i} exp(cum_i-cum_j)(q_i.k_j) v_j
// ---------------------------------------------------------------------------
__global__ void __launch_bounds__(256) gla_phaseC(const u16* __restrict__ Qb, const u16* __restrict__ Kb,
                                                  const u16* __restrict__ VT, const u16* __restrict__ SSb,
                                                  const float* __restrict__ LOGF, u16* __restrict__ Ob) {
  const int blk = blockIdx.x;
  const int bh = blk >> 5, c = blk & 31;
  const int b = bh >> 3, h = bh & 7;
  const int tid = threadIdx.x;
  const int wave = tid >> 6, lane = tid & 63;
  const int wr = wave >> 1, wc = wave & 1, l15 = lane & 15;
  const int q4i = (lane >> 4) * 4, q8 = (lane >> 4) * 8;
  __shared__ u16 SA[128 * 40];
  __shared__ u16 SB[128 * 40];
  __shared__ u16 Ps[128 * 136];
  __shared__ float cum[CHUNK_];
  __shared__ float cumE[CHUNK_];
  scan_chunk(LOGF + (size_t)bh * N_ + c * CHUNK_, cum, tid);
  if (tid < 128) cumE[tid] = __expf(cum[tid]);
  __syncthreads();
  const size_t rowbase = ((size_t)(b * N_ + c * CHUNK_)) * E_ + (size_t)h * R_;
  const u16* vtbase = VT + ((size_t)bh * R_) * N_ + (size_t)c * CHUNK_;
  const u16* ssbase = SSb + (size_t)blk * (R_ * R_);

  f32x4 acc[4][4];
#pragma unroll
  for (int i = 0; i < 4; i++)
#pragma unroll
    for (int j = 0; j < 4; j++) acc[i][j] = (f32x4){0.f, 0.f, 0.f, 0.f};

  // ---- S^T = K @ Q^T (row=j, col=i) ----
  for (int r0 = 0; r0 < R_; r0 += 32) {
    __syncthreads();
    stage32(SA, Kb + rowbase + r0, E_, tid);   // rows j
    stage32(SB, Qb + rowbase + r0, E_, tid);   // rows i
    __syncthreads();
    mfma16<false>(acc, SA, SB, wr, wc, l15, q8);
  }
  // ---- mask + decay -> Ps[i][j] ----
#pragma unroll
  for (int mi = 0; mi < 4; mi++) {
#pragma unroll
    for (int ni = 0; ni < 4; ni++) {
      int jb = wr * 64 + mi * 16 + q4i;
      int i = wc * 64 + ni * 16 + l15;
      float ci = cum[i];
      float4 cj = *(const float4*)&cum[jb];
      u16x4 pk;
      float cjv[4] = {cj.x, cj.y, cj.z, cj.w};
#pragma unroll
      for (int r = 0; r < 4; r++) {
        int j = jb + r;
        float w = (j <= i) ? __expf(ci - cjv[r]) : 0.f;
        pk[r] = f2b(acc[mi][ni][r] * w);
      }
      *(u16x4*)&Ps[i * 136 + jb] = pk;
    }
  }
  // ---- term1 (swapped): Q @ SS^T  (row=v, col=i) ----
#pragma unroll
  for (int i = 0; i < 4; i++)
#pragma unroll
    for (int j = 0; j < 4; j++) acc[i][j] = (f32x4){0.f, 0.f, 0.f, 0.f};
  for (int k0 = 0; k0 < R_; k0 += 32) {
    __syncthreads();
    stage32(SA, Qb + rowbase + k0, E_, tid);     // rows i
    stage32(SB, ssbase + k0, R_, tid);           // rows v (SS^T layout [v][k])
    __syncthreads();
    mfma16<true>(acc, SA, SB, wr, wc, l15, q8);
  }
  // scale by exp(cum_i)
#pragma unroll
  for (int mi = 0; mi < 4; mi++) {
    float ei = cumE[wr * 64 + mi * 16 + l15];
#pragma unroll
    for (int ni = 0; ni < 4; ni++)
#pragma unroll
      for (int r = 0; r < 4; r++) acc[mi][ni][r] *= ei;
  }
  // ---- term2 (swapped): acc += P @ V^T (row=v, col=i) ----
  for (int j0 = 0; j0 < CHUNK_; j0 += 32) {
    __syncthreads();
    stage32(SB, vtbase + j0, N_, tid);           // rows v
    __syncthreads();
    if (wr == 1 || j0 < 64) {                    // wr==0 waves: i<64 -> j>=64 all masked
      bf16x8 af[4], bf[4];
#pragma unroll
      for (int mi = 0; mi < 4; mi++)
        af[mi] = *(const bf16x8*)&Ps[(wr * 64 + mi * 16 + l15) * 136 + j0 + q8];
#pragma unroll
      for (int ni = 0; ni < 4; ni++)
        bf[ni] = *(const bf16x8*)&SB[(wc * 64 + ni * 16 + l15) * 40 + q8];
#pragma unroll
      for (int mi = 0; mi < 4; mi++)
#pragma unroll
        for (int ni = 0; ni < 4; ni++)
          acc[mi][ni] = __builtin_amdgcn_mfma_f32_16x16x32_bf16(bf[ni], af[mi], acc[mi][ni], 0, 0, 0);
    }
  }
  // ---- write O (bf16, row-major [m][E]): u16x4 along v at fixed i ----
#pragma unroll
  for (int mi = 0; mi < 4; mi++) {
#pragma unroll
    for (int ni = 0; ni < 4; ni++) {
      int i = wr * 64 + mi * 16 + l15;
      int vb = wc * 64 + ni * 16 + q4i;
      u16x4 pk;
#pragma unroll
      for (int r = 0; r < 4; r++) pk[r] = f2b(acc[mi][ni][r]);
      *(u16x4*)&Ob[rowbase + (size_t)i * E_ + vb] = pk;
    }
  }
}

// ---------------------------------------------------------------------------
// o = o * gate (both bf16); LayerNorm(weight-only, fp32 gamma) -> bf16
// ---------------------------------------------------------------------------
__global__ void __launch_bounds__(256) gate_ln(const u16* __restrict__ O, const u16* __restrict__ G,
                                               const float* __restrict__ gamma, u16* __restrict__ OLN) {
  int row = blockIdx.x, tid = threadIdx.x;
  u16x4 o4 = *(const u16x4*)(O + (size_t)row * E_ + tid * 4);
  u16x4 g4 = *(const u16x4*)(G + (size_t)row * E_ + tid * 4);
  float x0 = b2f(o4[0]) * b2f(g4[0]), x1 = b2f(o4[1]) * b2f(g4[1]);
  float x2 = b2f(o4[2]) * b2f(g4[2]), x3 = b2f(o4[3]) * b2f(g4[3]);
  float s = x0 + x1 + x2 + x3;
  float sq = x0 * x0 + x1 * x1 + x2 * x2 + x3 * x3;
  __shared__ float red[8];
#pragma unroll
  for (int m = 1; m < 64; m <<= 1) { s += __shfl_xor(s, m); sq += __shfl_xor(sq, m); }
  int wid = tid >> 6;
  if ((tid & 63) == 0) { red[wid] = s; red[4 + wid] = sq; }
  __syncthreads();
  s = red[0] + red[1] + red[2] + red[3];
  sq = red[4] + red[5] + red[6] + red[7];
  float mu = s * (1.f / 1024.f);
  float var = sq * (1.f / 1024.f) - mu * mu;
  float rs = rsqrtf(var + 1e-5f);
  int e = tid * 4;
  u16x4 r4;
  r4[0] = f2b((x0 - mu) * rs * gamma[e + 0]);
  r4[1] = f2b((x1 - mu) * rs * gamma[e + 1]);
  r4[2] = f2b((x2 - mu) * rs * gamma[e + 2]);
  r4[3] = f2b((x3 - mu) * rs * gamma[e + 3]);
  *(u16x4*)(OLN + (size_t)row * E_ + e) = r4;
}

// ---------------------------------------------------------------------------
extern "C" void kernel_launch(void* const* d_in, const int* in_sizes, int n_in,
                              void* d_out, int out_size, void* d_ws, size_t ws_size,
                              hipStream_t stream) {
  (void)in_sizes; (void)n_in; (void)out_size; (void)ws_size;
  const float* x   = (const float*)d_in[0];
  const float* llb = (const float*)d_in[1];
  const float* Wq  = (const float*)d_in[2];
  const float* Wk  = (const float*)d_in[3];
  const float* Wv  = (const float*)d_in[4];
  const float* Wf  = (const float*)d_in[5];
  const float* Wb1 = (const float*)d_in[6];
  const float* Wb2 = (const float*)d_in[7];
  const float* Wg1 = (const float*)d_in[8];
  const float* Wg2 = (const float*)d_in[9];
  const float* gm  = (const float*)d_in[10];
  const float* Wo  = (const float*)d_in[11];
  float* out = (float*)d_out;

  char* ws = (char*)d_ws;
  const size_t SZB = (size_t)M_ * E_ * 2;            // 16.78 MB bf16 [M,E]
  u16*   Qb    = (u16*)(ws + 0 * SZB);               // q bf16 (OLN overlay later)
  u16*   Kb    = (u16*)(ws + 1 * SZB);
  u16*   KT    = (u16*)(ws + 2 * SZB);               // [B,H,R,N]
  u16*   VT    = (u16*)(ws + 3 * SZB);               // [B,H,R,N]
  u16*   BETAb = (u16*)(ws + 4 * SZB);               // beta -> O overlay
  u16*   GATEb = (u16*)(ws + 5 * SZB);
  u16*   SSb   = (u16*)(ws + 6 * SZB);               // chunk-start states bf16 [v][k]
  u16*   XB    = (u16*)(ws + 7 * SZB);
  u16*   U     = (u16*)(ws + 8 * SZB);               // bf16 [512][128][128]
  char*  tail  = ws + 8 * SZB + (size_t)BH_ * NC_ * R_ * R_ * 2;
  u16*   Wcat  = (u16*)tail;                         // [3456][1024]
  u16*   Wcat2 = Wcat + (size_t)3456 * 1024;         // [2048][256]
  u16*   WOb   = Wcat2 + (size_t)2048 * 256;         // [1024][1024]
  u16*   T1    = WOb + (size_t)E_ * E_;              // [M,256]
  float* LOGF  = (float*)(T1 + (size_t)M_ * 256);
  float* DC    = LOGF + (size_t)BH_ * N_;
  u16*   Ob    = BETAb;                              // overlay (beta dead after householder)
  u16*   OLN   = Qb;                                 // overlay (q dead after phaseC)

  CvtArgs ca;
  ca.src[0] = x;   ca.dst[0]  = XB;
  ca.src[1] = Wq;  ca.dst[1]  = Wcat;
  ca.src[2] = Wk;  ca.dst[2]  = Wcat + (size_t)1024 * 1024;
  ca.src[3] = Wv;  ca.dst[3]  = Wcat + (size_t)2048 * 1024;
  ca.src[4] = Wf;  ca.dst[4]  = Wcat + (size_t)3328 * 1024;
  ca.src[5] = Wb1; ca.dst[5]  = Wcat + (size_t)3072 * 1024;
  ca.src[6] = Wb2; ca.dst[6]  = Wcat2;
  ca.src[7] = Wg1; ca.dst[7]  = Wcat + (size_t)3200 * 1024;
  ca.src[8] = Wg2; ca.dst[8]  = Wcat2;
  ca.src[9] = Wo;  ca.dst[9]  = WOb;
  ca.dst[10] = Wcat + (size_t)3336 * 1024;           // zero pad rows

  dim3 blk(256);
  cvt_all<<<dim3(12928), blk, 0, stream>>>(ca);
  mega_gemm<<<dim3(27, 64), blk, 0, stream>>>(XB, Wcat, llb, Qb, Kb, KT, VT, T1, LOGF);
  bg_gemm<<<dim3(64, 16), blk, 0, stream>>>(T1, Wcat2, BETAb, GATEb);
  householder<<<dim3(M_), blk, 0, stream>>>(Qb, BETAb);
  gla_phaseA<<<dim3(BH_ * NC_), blk, 0, stream>>>(KT, VT, LOGF, U, DC);
  gla_phaseB<<<dim3(BH_ * 16384 / 256), blk, 0, stream>>>(U, DC, SSb);
  gla_phaseC<<<dim3(BH_ * NC_), blk, 0, stream>>>(Qb, Kb, VT, SSb, LOGF, Ob);
  gate_ln<<<dim3(M_), blk, 0, stream>>>(Ob, GATEb, gm, OLN);
  out_gemm<<<dim3(64, 8), blk, 0, stream>>>(OLN, WOb, out);
}

// Round 5
// 304.869 us; speedup vs baseline: 1.0443x; 1.0171x over previous
//
#include <hip/hip_runtime.h>
#include <hip/hip_bf16.h>

using u16 = unsigned short;
typedef __attribute__((ext_vector_type(8))) short bf16x8;
typedef __attribute__((ext_vector_type(4))) float f32x4;
typedef __attribute__((ext_vector_type(8))) u16 u16x8;
typedef __attribute__((ext_vector_type(4))) u16 u16x4;

#define B_ 2
#define N_ 4096
#define E_ 1024
#define R_ 128
#define H_ 8
#define M_ 8192      // B*N
#define CHUNK_ 128
#define NC_ 32       // N/CHUNK
#define BH_ 16       // B*H

__device__ __forceinline__ float b2f(u16 u) { return __uint_as_float(((unsigned)u) << 16); }
__device__ __forceinline__ u16 f2b(float f) {
  unsigned u = __float_as_uint(f);
  return (u16)((u + 0x7fffu + ((u >> 16) & 1u)) >> 16);   // RNE
}
// fast sigmoid (native v_exp + v_rcp; rel err ~2^-21, fine for bf16 out)
__device__ __forceinline__ float sigm(float x) {
  return __builtin_amdgcn_rcpf(1.0f + __expf(-x));
}

#define GLDS(g, l) __builtin_amdgcn_global_load_lds( \
    (const __attribute__((address_space(1))) unsigned int*)(g), \
    (__attribute__((address_space(3))) unsigned int*)(l), 16, 0, 0)

// ---------------------------------------------------------------------------
// fp32 -> bf16 conversion (x, weights into Wcat/Wcat2/Wo, zero pad).
// ---------------------------------------------------------------------------
struct CvtArgs {
  const float* src[10];
  u16* dst[11];
};

__global__ void __launch_bounds__(256) cvt_all(CvtArgs a) {
  int idx = blockIdx.x * 256 + threadIdx.x;   // float4-granule index; grid exact
  const int SZ[11] = {2097152, 262144, 262144, 262144, 2048,
                      32768, 32768, 32768, 32768, 262144, 30720};
  int off = idx, seg = 0;
#pragma unroll
  for (int i = 0; i < 10; i++) {
    if (seg == i && off >= SZ[i]) { off -= SZ[i]; seg = i + 1; }
  }
  u16x4 z = (u16x4){0, 0, 0, 0};
  if (seg == 10) { ((u16x4*)a.dst[10])[off] = z; return; }   // Wcat pad rows
  float4 v = ((const float4*)a.src[seg])[off];
  u16x4 r;
  r[0] = f2b(v.x); r[1] = f2b(v.y); r[2] = f2b(v.z); r[3] = f2b(v.w);
  if (seg == 6) {              // Wb2 -> Wcat2 rows 0-1023, cols 0-127 (+zero cols 128-255)
    int n = off >> 5, c = off & 31;
    u16x4* W2 = (u16x4*)a.dst[6];
    W2[n * 64 + c] = r; W2[n * 64 + 32 + c] = z;
  } else if (seg == 8) {       // Wg2 -> Wcat2 rows 1024-2047, cols 128-255 (+zero cols 0-127)
    int n = off >> 5, c = off & 31;
    u16x4* W2 = (u16x4*)a.dst[8];
    W2[(1024 + n) * 64 + 32 + c] = r; W2[(1024 + n) * 64 + c] = z;
  } else {
    ((u16x4*)a.dst[seg])[off] = r;
  }
}

// ---------------------------------------------------------------------------
// BK=64 GEMM K-loop, 128x128 tile, 4 waves (kept for bg_gemm / out_gemm).
// ---------------------------------------------------------------------------
template<bool SWAP>
__device__ __forceinline__ void mfma_panel(f32x4 (&acc)[4][4], const u16* A, const u16* Bm,
                                           int wr, int wc, int l15, int q8) {
  bf16x8 af[4], bf[4];
#pragma unroll
  for (int mi = 0; mi < 4; mi++) af[mi] = *(const bf16x8*)&A[(wr * 64 + mi * 16 + l15) * 32 + q8];
#pragma unroll
  for (int ni = 0; ni < 4; ni++) bf[ni] = *(const bf16x8*)&Bm[(wc * 64 + ni * 16 + l15) * 32 + q8];
#pragma unroll
  for (int mi = 0; mi < 4; mi++)
#pragma unroll
    for (int ni = 0; ni < 4; ni++)
      acc[mi][ni] = SWAP
        ? __builtin_amdgcn_mfma_f32_16x16x32_bf16(bf[ni], af[mi], acc[mi][ni], 0, 0, 0)
        : __builtin_amdgcn_mfma_f32_16x16x32_bf16(af[mi], bf[ni], acc[mi][ni], 0, 0, 0);
}

template<bool SWAP, int K>
__device__ __forceinline__ void gemm_loop(const u16* __restrict__ X, const u16* __restrict__ W,
                                          int m0, int n0,
                                          u16* As, u16* Bs, f32x4 (&acc)[4][4], int tid) {
  const int wave = tid >> 6, lane = tid & 63;
  const int wr = wave >> 1, wc = wave & 1, l15 = lane & 15, q8 = (lane >> 4) * 8;
  const u16* Ap = X + (size_t)(m0 + wave * 32 + (lane >> 2)) * K + (lane & 3) * 8;
  const u16* Bp = W + (size_t)(n0 + wave * 32 + (lane >> 2)) * K + (lane & 3) * 8;
  u16* A0 = As + wave * 1024;
  u16* B0 = Bs + wave * 1024;
#pragma unroll
  for (int k0 = 0; k0 < K; k0 += 64) {
    GLDS(Ap + k0,                    A0);
    GLDS(Ap + 16 * (size_t)K + k0,   A0 + 512);
    GLDS(Ap + k0 + 32,               A0 + 4096);
    GLDS(Ap + 16 * (size_t)K + k0 + 32, A0 + 4608);
    GLDS(Bp + k0,                    B0);
    GLDS(Bp + 16 * (size_t)K + k0,   B0 + 512);
    GLDS(Bp + k0 + 32,               B0 + 4096);
    GLDS(Bp + 16 * (size_t)K + k0 + 32, B0 + 4608);
    __syncthreads();
    mfma_panel<SWAP>(acc, As, Bs, wr, wc, l15, q8);
    mfma_panel<SWAP>(acc, As + 4096, Bs + 4096, wr, wc, l15, q8);
    __syncthreads();
  }
}

// ---------------------------------------------------------------------------
// mega_gemm K-loop: 128x128 tile / BK=32 double-buffered stage-ahead,
// 4 waves, K=1024, one __syncthreads per K-tile (implicit vmcnt/lgkm drain is
// the full dbuf ledger). 16-B slot swizzle slot = g ^ ((row ^ row>>2)&3),
// applied to the GLOBAL source col (GLDS dest linear) and the ds_read slot
// (same involution both sides).
// LDS byte layout in sh: A0 @0, B0 @8192, A1 @16384, B1 @24576 (32 KB used).
// acc mapping identical to round-0 gemm_loop:
//   SWAP:  acc[mi][ni][r] = C[m0+wr*64+mi*16+l15][n0+wc*64+ni*16+q4+r]
//   !SWAP: acc[mi][ni][r] = C[m0+wr*64+mi*16+q4+r][n0+wc*64+ni*16+l15]
// ---------------------------------------------------------------------------
template<bool SWAP>
__device__ __forceinline__ void gemm128_dbuf(const u16* __restrict__ X, const u16* __restrict__ W,
                                             int m0, int n0, u16* sh, f32x4 (&acc)[4][4], int tid) {
  const int w = tid >> 6, lane = tid & 63;
  const int wr = w >> 1, wc = w & 1;
  const int l15 = lane & 15, g = lane >> 4;
  const int lrow = tid >> 2;                                  // 0..63
  const int scol = (tid & 3) ^ ((lrow ^ (lrow >> 2)) & 3);    // pre-swizzled src slot
  const u16* pA0 = X + (size_t)(m0 + lrow) * 1024 + scol * 8;
  const u16* pA1 = X + (size_t)(m0 + 64 + lrow) * 1024 + scol * 8;
  const u16* pB0 = W + (size_t)(n0 + lrow) * 1024 + scol * 8;
  const u16* pB1 = W + (size_t)(n0 + 64 + lrow) * 1024 + scol * 8;
  const int sw = (g ^ (l15 & 3) ^ ((l15 >> 2) & 3)) << 4;     // swizzled read slot (bytes)
  const int abase = (wr * 64 + l15) * 64 + sw;                // bytes into A buf
  const int bbase = (wc * 64 + l15) * 64 + sw;                // bytes into B buf

#define STG128(T, bi) do {                                                      \
    char* Ad_ = (char*)sh + (bi) * 16384;                                       \
    char* Bd_ = (char*)sh + 8192 + (bi) * 16384;                                \
    GLDS(pA0 + (size_t)(T) * 32, Ad_ + w * 1024);                               \
    GLDS(pA1 + (size_t)(T) * 32, Ad_ + 4096 + w * 1024);                        \
    GLDS(pB0 + (size_t)(T) * 32, Bd_ + w * 1024);                               \
    GLDS(pB1 + (size_t)(T) * 32, Bd_ + 4096 + w * 1024);                        \
  } while (0)

  STG128(0, 0);
  __syncthreads();                   // implicit vmcnt(0): tile 0 landed

#pragma unroll 2
  for (int t = 0; t < 32; ++t) {
    if (t < 31) STG128(t + 1, (t + 1) & 1);
    const char* Ab = (const char*)sh + (t & 1) * 16384;
    const char* Bb = (const char*)sh + 8192 + (t & 1) * 16384;
    bf16x8 af[4], bf[4];
#pragma unroll
    for (int mi = 0; mi < 4; mi++) af[mi] = *(const bf16x8*)(Ab + abase + mi * 1024);
#pragma unroll
    for (int ni = 0; ni < 4; ni++) bf[ni] = *(const bf16x8*)(Bb + bbase + ni * 1024);
    __builtin_amdgcn_s_setprio(1);
#pragma unroll
    for (int mi = 0; mi < 4; mi++)
#pragma unroll
      for (int ni = 0; ni < 4; ni++)
        acc[mi][ni] = SWAP
          ? __builtin_amdgcn_mfma_f32_16x16x32_bf16(bf[ni], af[mi], acc[mi][ni], 0, 0, 0)
          : __builtin_amdgcn_mfma_f32_16x16x32_bf16(af[mi], bf[ni], acc[mi][ni], 0, 0, 0);
    __builtin_amdgcn_s_setprio(0);
    __syncthreads();                 // drains stage of t+1 + protects dbuf swap
  }
#undef STG128
}

// ---------------------------------------------------------------------------
// Mega-GEMM: X[M,1024] @ Wcat[3456,1024]^T. Flat grid 1728 with XCD-chunked
// mapping: g = (blk&7)*216 + blk>>3 (bijective, 1728%8==0); ny = g%27,
// my = g/27. Each XCD owns 8 contiguous m-tiles x all 27 ny: X slab = 2 MB
// (L2-resident per XCD, fetched once) and Wcat tiles shared across the ~5
// concurrent m-rows -> stage sources are mostly L2 hits, which the BK=32
// dbuf stage-ahead covers.
//  ny 0-7   (swapped): silu -> Qb u16x4
//  ny 8-15  (swapped): silu -> Kb u16x4 + KT via LDS scalar-transpose
//  ny 16-23 (unswapped): -> VT direct u16x4 (C/D rows run along m = seq dim)
//  ny 24-25 (swapped): -> T1 u16x4
//  ny 26    (swapped): f logits -> LOGF
// Ts transpose stride 134 u16 (67 dwords, gcd(67,32)=1 -> conflict-free row
// phasing; was 136 = the 7.14M-conflict hotspot).
// ---------------------------------------------------------------------------
__global__ void __launch_bounds__(256, 4) mega_gemm(const u16* __restrict__ X, const u16* __restrict__ Wcat,
                                                    const float* __restrict__ llb,
                                                    u16* __restrict__ Qb, u16* __restrict__ Kb,
                                                    u16* __restrict__ KT, u16* __restrict__ VT,
                                                    u16* __restrict__ T1, float* __restrict__ LOGF) {
  __shared__ u16 sh[17408];           // K-loop uses first 32 KB; Ts overlays (stride 134)
  u16* Ts = sh;
  const int tid = threadIdx.x;
  const int blk = blockIdx.x;
  const int gidx = (blk & 7) * 216 + (blk >> 3);
  const int ny = gidx % 27, myt = gidx / 27;
  const int m0 = myt * 128, n0 = ny * 128;
  const int wave = tid >> 6, lane = tid & 63;
  const int wr = wave >> 1, wc = wave & 1, l15 = lane & 15, q4 = (lane >> 4) * 4;
  f32x4 acc[4][4];
#pragma unroll
  for (int i = 0; i < 4; i++)
#pragma unroll
    for (int j = 0; j < 4; j++) acc[i][j] = (f32x4){0.f, 0.f, 0.f, 0.f};

  if (ny >= 16 && ny < 24) {
    // ---- V block: unswapped -> rows (q4+r) = m-dim -> direct u16x4 into VT ----
    gemm128_dbuf<false>(X, Wcat, m0, n0, sh, acc, tid);
#pragma unroll
    for (int mi = 0; mi < 4; mi++) {
#pragma unroll
      for (int ni = 0; ni < 4; ni++) {
        int col = n0 - 2048 + wc * 64 + ni * 16 + l15;   // v-dim 0..1023
        int rbase = m0 + wr * 64 + mi * 16 + q4;         // m-dim (4 consecutive)
        int head = col >> 7, rl = col & 127;
        int bb = rbase >> 12, nseq = rbase & (N_ - 1);
        u16x4 pk;
#pragma unroll
        for (int r = 0; r < 4; r++) pk[r] = f2b(acc[mi][ni][r]);
        *(u16x4*)&VT[((size_t)(bb * H_ + head) * R_ + rl) * N_ + nseq] = pk;
      }
    }
    return;
  }

  gemm128_dbuf<true>(X, Wcat, m0, n0, sh, acc, tid);

  if (ny == 26) {                     // decay logits -> LOGF
    // n-local = wc*64 + ni*16 + q4 + r < 8  =>  wc==0, ni==0, q4 in {0,4}
    if (wc == 0 && (lane >> 4) < 2) {
#pragma unroll
      for (int mi = 0; mi < 4; mi++) {
        int mcol = m0 + wr * 64 + mi * 16 + l15;
        int bb = mcol >> 12, nseq = mcol & (N_ - 1);
#pragma unroll
        for (int r = 0; r < 4; r++) {
          int h = q4 + r;             // 0..7
          float lb = __expf(llb[h]);
          LOGF[(size_t)(bb * H_ + h) * N_ + nseq] =
              __logf(lb + (1.f - lb) * sigm(acc[mi][0][r]));
        }
      }
    }
    return;
  }

  // swapped: lane holds 4 consecutive n (nb..nb+3) at fixed m (mcol)
#pragma unroll
  for (int mi = 0; mi < 4; mi++) {
#pragma unroll
    for (int ni = 0; ni < 4; ni++) {
      int nb = n0 + wc * 64 + ni * 16 + q4;
      int mcol = m0 + wr * 64 + mi * 16 + l15;
      u16x4 pk;
#pragma unroll
      for (int r = 0; r < 4; r++) {
        float v = acc[mi][ni][r];
        if (ny < 16) v = v * sigm(v);
        pk[r] = f2b(v);
      }
      if (ny < 8) {
        *(u16x4*)&Qb[(size_t)mcol * E_ + nb] = pk;
      } else if (ny < 16) {
        *(u16x4*)&Kb[(size_t)mcol * E_ + nb - 1024] = pk;
        int nl = nb - n0;             // local k-dim 0..127
        int ml = mcol - m0;           // local m 0..127
#pragma unroll
        for (int r = 0; r < 4; r++) Ts[(nl + r) * 134 + ml] = pk[r];
      } else {                        // ny 24/25 -> T1
        *(u16x4*)&T1[(size_t)mcol * 256 + nb - 3072] = pk;
      }
    }
  }

  if (ny >= 8 && ny < 16) {           // KT copy-out from Ts[nl][ml]
    __syncthreads();
    int head = (n0 - 1024) >> 7;
    int bb = m0 >> 12, nloc = m0 & (N_ - 1);
    size_t base = ((size_t)(bb * H_ + head) * R_) * N_ + nloc;
#pragma unroll
    for (int p = 0; p < 8; p++) {
      int nl = p * 16 + (tid >> 4);
      int m8 = (tid & 15) * 8;
      u16x8 v = *(const u16x8*)&Ts[nl * 134 + m8];
      *(u16x8*)&KT[base + (size_t)nl * N_ + m8] = v;
    }
  }
}

// ---------------------------------------------------------------------------
// beta+gate GEMM (swapped): T1[M,256] @ Wcat2[2048,256]^T.
// ---------------------------------------------------------------------------
__global__ void __launch_bounds__(256) bg_gemm(const u16* __restrict__ T1, const u16* __restrict__ W2,
                                               u16* __restrict__ BETA, u16* __restrict__ GATE) {
  __shared__ u16 As[8192];
  __shared__ u16 Bs[8192];
  const int tid = threadIdx.x;
  const int m0 = blockIdx.x * 128;
  const int n0 = blockIdx.y * 128;
  f32x4 acc[4][4];
#pragma unroll
  for (int i = 0; i < 4; i++)
#pragma unroll
    for (int j = 0; j < 4; j++) acc[i][j] = (f32x4){0.f, 0.f, 0.f, 0.f};
  gemm_loop<true, 256>(T1, W2, m0, n0, As, Bs, acc, tid);
  const int wave = tid >> 6, lane = tid & 63;
  const int wr = wave >> 1, wc = wave & 1, l15 = lane & 15, q4 = (lane >> 4) * 4;
#pragma unroll
  for (int mi = 0; mi < 4; mi++) {
#pragma unroll
    for (int ni = 0; ni < 4; ni++) {
      int nb = n0 + wc * 64 + ni * 16 + q4;
      int mcol = m0 + wr * 64 + mi * 16 + l15;
      u16x4 pk;
      if (nb < 1024) {
#pragma unroll
        for (int r = 0; r < 4; r++) {
          float v = acc[mi][ni][r];
          pk[r] = f2b(v * sigm(v));
        }
        *(u16x4*)&BETA[(size_t)mcol * E_ + nb] = pk;
      } else {
#pragma unroll
        for (int r = 0; r < 4; r++) pk[r] = f2b(sigm(acc[mi][ni][r]));
        *(u16x4*)&GATE[(size_t)mcol * E_ + nb - 1024] = pk;
      }
    }
  }
}

// ---------------------------------------------------------------------------
// Output GEMM (swapped): OLN[M,1024] @ Wo[1024,1024]^T -> fp32 out, float4.
// ---------------------------------------------------------------------------
__global__ void __launch_bounds__(256) out_gemm(const u16* __restrict__ X, const u16* __restrict__ W,
                                                float* __restrict__ C) {
  __shared__ u16 As[8192];
  __shared__ u16 Bs[8192];
  const int tid = threadIdx.x;
  const int m0 = blockIdx.x * 128;
  const int n0 = blockIdx.y * 128;
  f32x4 acc[4][4];
#pragma unroll
  for (int i = 0; i < 4; i++)
#pragma unroll
    for (int j = 0; j < 4; j++) acc[i][j] = (f32x4){0.f, 0.f, 0.f, 0.f};
  gemm_loop<true, 1024>(X, W, m0, n0, As, Bs, acc, tid);
  const int wave = tid >> 6, lane = tid & 63;
  const int wr = wave >> 1, wc = wave & 1, l15 = lane & 15, q4 = (lane >> 4) * 4;
#pragma unroll
  for (int mi = 0; mi < 4; mi++) {
#pragma unroll
    for (int ni = 0; ni < 4; ni++) {
      int nb = n0 + wc * 64 + ni * 16 + q4;
      int mcol = m0 + wr * 64 + mi * 16 + l15;
      *(f32x4*)&C[(size_t)mcol * E_ + nb] = acc[mi][ni];
    }
  }
}

// ---------------------------------------------------------------------------
// Householder on bf16 q (in place)
// ---------------------------------------------------------------------------
__global__ void __launch_bounds__(256) householder(u16* __restrict__ Q, const u16* __restrict__ BETA) {
  int row = blockIdx.x;
  int tid = threadIdx.x;
  u16* q = Q + (size_t)row * E_;
  const u16* bt = BETA + (size_t)row * E_;
  u16x4 q4 = *(const u16x4*)(q + tid * 4);
  u16x4 b4 = *(const u16x4*)(bt + tid * 4);
  float qv[4], bv[4];
#pragma unroll
  for (int i = 0; i < 4; i++) { qv[i] = b2f(q4[i]); bv[i] = b2f(b4[i]); }
  float ss = bv[0]*bv[0] + bv[1]*bv[1] + bv[2]*bv[2] + bv[3]*bv[3];
  float qd = qv[0]*bv[0] + qv[1]*bv[1] + qv[2]*bv[2] + qv[3]*bv[3];
  __shared__ float red[8];
#pragma unroll
  for (int m = 1; m < 64; m <<= 1) { ss += __shfl_xor(ss, m); qd += __shfl_xor(qd, m); }
  int wid = tid >> 6;
  if ((tid & 63) == 0) { red[wid] = ss; red[4 + wid] = qd; }
  __syncthreads();
  ss = red[0] + red[1] + red[2] + red[3];
  qd = red[4] + red[5] + red[6] + red[7];
  float coef = 2.f * qd / (ss + 1e-12f);
  const float scale = 0.08838834764831845f;  // 128^-0.5 folded in
  u16x4 o4;
#pragma unroll
  for (int i = 0; i < 4; i++) o4[i] = f2b((qv[i] - coef * bv[i]) * scale);
  *(u16x4*)(q + tid * 4) = o4;
}

// inclusive scan of the 128 log-decay values of one chunk into cum[] (wave 0)
__device__ __forceinline__ void scan_chunk(const float* __restrict__ lf, float* cum, int tid) {
  if (tid < 64) {
    float a = lf[tid], b = lf[tid + 64];
#pragma unroll
    for (int off = 1; off < 64; off <<= 1) {
      float t = __shfl_up(a, off);  if (tid >= off) a += t;
      float t2 = __shfl_up(b, off); if (tid >= off) b += t2;
    }
    b += __shfl(a, 63);
    cum[tid] = a; cum[tid + 64] = b;
  }
  __syncthreads();
}

// stage a [128 x 32] bf16 slab (row stride `stride` elements) into LDS [128][40]
__device__ __forceinline__ void stage32(u16* dst, const u16* src, size_t stride, int tid) {
  int r0 = tid >> 2, c8 = (tid & 3) * 8;
  *(u16x8*)&dst[(size_t)r0 * 40 + c8] = *(const u16x8*)&src[(size_t)r0 * stride + c8];
  int r1 = r0 + 64;
  *(u16x8*)&dst[(size_t)r1 * 40 + c8] = *(const u16x8*)&src[(size_t)r1 * stride + c8];
}

// same, scaling column j (slab-local) by w[j0 + j]
__device__ __forceinline__ void stage32_scaled(u16* dst, const u16* src, size_t stride,
                                               const float* w, int j0, int tid) {
  int c8 = (tid & 3) * 8;
  float wv[8];
#pragma unroll
  for (int i = 0; i < 8; i++) wv[i] = w[j0 + c8 + i];
#pragma unroll
  for (int rr = 0; rr < 128; rr += 64) {
    int r = rr + (tid >> 2);
    u16x8 raw = *(const u16x8*)&src[(size_t)r * stride + c8];
    u16x8 o;
#pragma unroll
    for (int i = 0; i < 8; i++) o[i] = f2b(b2f(raw[i]) * wv[i]);
    *(u16x8*)&dst[(size_t)r * 40 + c8] = o;
  }
}

// one K=32 MFMA step over a 128x128 output (4 waves), A/B slabs in LDS [128][40]
template<bool SWAP>
__device__ __forceinline__ void mfma16(f32x4 (&acc)[4][4], const u16* A, const u16* Bm,
                                       int wr, int wc, int l15, int q8) {
  bf16x8 af[4], bf[4];
#pragma unroll
  for (int mi = 0; mi < 4; mi++) af[mi] = *(const bf16x8*)&A[(wr * 64 + mi * 16 + l15) * 40 + q8];
#pragma unroll
  for (int ni = 0; ni < 4; ni++) bf[ni] = *(const bf16x8*)&Bm[(wc * 64 + ni * 16 + l15) * 40 + q8];
#pragma unroll
  for (int mi = 0; mi < 4; mi++)
#pragma unroll
    for (int ni = 0; ni < 4; ni++)
      acc[mi][ni] = SWAP
        ? __builtin_amdgcn_mfma_f32_16x16x32_bf16(bf[ni], af[mi], acc[mi][ni], 0, 0, 0)
        : __builtin_amdgcn_mfma_f32_16x16x32_bf16(af[mi], bf[ni], acc[mi][ni], 0, 0, 0);
}

// ---------------------------------------------------------------------------
// Phase A (MFMA, swapped): acc[mi][ni][r] = D[k = wc*64+ni*16+q4+r][v = wr*64+mi*16+l15]
// = sum_j KTw[k][j] VT[v][j]  ->  u16x4 (bf16) store at U[v][k..k+3].
// ---------------------------------------------------------------------------
__global__ void __launch_bounds__(256) gla_phaseA(const u16* __restrict__ KT, const u16* __restrict__ VT,
                                                  const float* __restrict__ LOGF,
                                                  u16* __restrict__ U, float* __restrict__ DC) {
  const int blk = blockIdx.x;
  const int bh = blk >> 5, c = blk & 31;
  const int tid = threadIdx.x;
  const int wave = tid >> 6, lane = tid & 63;
  const int wr = wave >> 1, wc = wave & 1, l15 = lane & 15, q8 = (lane >> 4) * 8;
  __shared__ u16 SA[128 * 40];
  __shared__ u16 SB[128 * 40];
  __shared__ float cum[CHUNK_];
  __shared__ float wd[CHUNK_];
  scan_chunk(LOGF + (size_t)bh * N_ + c * CHUNK_, cum, tid);
  if (tid < 128) wd[tid] = __expf(cum[127] - cum[tid]);
  __syncthreads();
  const u16* vbase = VT + ((size_t)bh * R_) * N_ + (size_t)c * CHUNK_;
  const u16* kbase = KT + ((size_t)bh * R_) * N_ + (size_t)c * CHUNK_;
  f32x4 acc[4][4];
#pragma unroll
  for (int i = 0; i < 4; i++)
#pragma unroll
    for (int j = 0; j < 4; j++) acc[i][j] = (f32x4){0.f, 0.f, 0.f, 0.f};
  for (int j0 = 0; j0 < CHUNK_; j0 += 32) {
    __syncthreads();
    stage32(SA, vbase + j0, N_, tid);
    stage32_scaled(SB, kbase + j0, N_, wd, j0, tid);
    __syncthreads();
    mfma16<true>(acc, SA, SB, wr, wc, l15, q8);
  }
  u16* Up = U + (size_t)blk * (R_ * R_);
  const int q4 = (lane >> 4) * 4;
#pragma unroll
  for (int mi = 0; mi < 4; mi++) {
#pragma unroll
    for (int ni = 0; ni < 4; ni++) {
      int v = wr * 64 + mi * 16 + l15;
      int kb = wc * 64 + ni * 16 + q4;
      u16x4 pk;
#pragma unroll
      for (int r = 0; r < 4; r++) pk[r] = f2b(acc[mi][ni][r]);
      *(u16x4*)&Up[(size_t)v * R_ + kb] = pk;
    }
  }
  if (tid == 0) DC[blk] = __expf(cum[127]);
}

// ---------------------------------------------------------------------------
// Phase B: propagate chunk-start states; U bf16 [v][k] -> SS bf16 [v][k]
// ---------------------------------------------------------------------------
__global__ void __launch_bounds__(256) gla_phaseB(const u16* __restrict__ U, const float* __restrict__ DC,
                                                  u16* __restrict__ SSb) {
  int idx = blockIdx.x * 256 + threadIdx.x;
  int bh = idx >> 14;
  int e = idx & 16383;
  float s = 0.f;
  for (int c = 0; c < NC_; c++) {
    size_t off = ((size_t)bh * NC_ + c) * 16384 + e;
    SSb[off] = f2b(s);
    s = DC[bh * NC_ + c] * s + b2f(U[off]);
  }
}

// ---------------------------------------------------------------------------
// Phase C (MFMA): o_i = exp(cum_i)*q_i@Sstart + sum_{j<=i} exp(cum_i-cum_j)(q_i.k_j) v_j
// ---------------------------------------------------------------------------
__global__ void __launch_bounds__(256) gla_phaseC(const u16* __restrict__ Qb, const u16* __restrict__ Kb,
                                                  const u16* __restrict__ VT, const u16* __restrict__ SSb,
                                                  const float* __restrict__ LOGF, u16* __restrict__ Ob) {
  const int blk = blockIdx.x;
  const int bh = blk >> 5, c = blk & 31;
  const int b = bh >> 3, h = bh & 7;
  const int tid = threadIdx.x;
  const int wave = tid >> 6, lane = tid & 63;
  const int wr = wave >> 1, wc = wave & 1, l15 = lane & 15;
  const int q4i = (lane >> 4) * 4, q8 = (lane >> 4) * 8;
  __shared__ u16 SA[128 * 40];
  __shared__ u16 SB[128 * 40];
  __shared__ u16 Ps[128 * 136];
  __shared__ float cum[CHUNK_];
  __shared__ float cumE[CHUNK_];
  scan_chunk(LOGF + (size_t)bh * N_ + c * CHUNK_, cum, tid);
  if (tid < 128) cumE[tid] = __expf(cum[tid]);
  __syncthreads();
  const size_t rowbase = ((size_t)(b * N_ + c * CHUNK_)) * E_ + (size_t)h * R_;
  const u16* vtbase = VT + ((size_t)bh * R_) * N_ + (size_t)c * CHUNK_;
  const u16* ssbase = SSb + (size_t)blk * (R_ * R_);

  f32x4 acc[4][4];
#pragma unroll
  for (int i = 0; i < 4; i++)
#pragma unroll
    for (int j = 0; j < 4; j++) acc[i][j] = (f32x4){0.f, 0.f, 0.f, 0.f};

  // ---- S^T = K @ Q^T (row=j, col=i) ----
  for (int r0 = 0; r0 < R_; r0 += 32) {
    __syncthreads();
    stage32(SA, Kb + rowbase + r0, E_, tid);   // rows j
    stage32(SB, Qb + rowbase + r0, E_, tid);   // rows i
    __syncthreads();
    mfma16<false>(acc, SA, SB, wr, wc, l15, q8);
  }
  // ---- mask + decay -> Ps[i][j] ----
#pragma unroll
  for (int mi = 0; mi < 4; mi++) {
#pragma unroll
    for (int ni = 0; ni < 4; ni++) {
      int jb = wr * 64 + mi * 16 + q4i;
      int i = wc * 64 + ni * 16 + l15;
      float ci = cum[i];
      float4 cj = *(const float4*)&cum[jb];
      u16x4 pk;
      float cjv[4] = {cj.x, cj.y, cj.z, cj.w};
#pragma unroll
      for (int r = 0; r < 4; r++) {
        int j = jb + r;
        float w = (j <= i) ? __expf(ci - cjv[r]) : 0.f;
        pk[r] = f2b(acc[mi][ni][r] * w);
      }
      *(u16x4*)&Ps[i * 136 + jb] = pk;
    }
  }
  // ---- term1 (swapped): Q @ SS^T  (row=v, col=i) ----
#pragma unroll
  for (int i = 0; i < 4; i++)
#pragma unroll
    for (int j = 0; j < 4; j++) acc[i][j] = (f32x4){0.f, 0.f, 0.f, 0.f};
  for (int k0 = 0; k0 < R_; k0 += 32) {
    __syncthreads();
    stage32(SA, Qb + rowbase + k0, E_, tid);     // rows i
    stage32(SB, ssbase + k0, R_, tid);           // rows v (SS^T layout [v][k])
    __syncthreads();
    mfma16<true>(acc, SA, SB, wr, wc, l15, q8);
  }
  // scale by exp(cum_i)
#pragma unroll
  for (int mi = 0; mi < 4; mi++) {
    float ei = cumE[wr * 64 + mi * 16 + l15];
#pragma unroll
    for (int ni = 0; ni < 4; ni++)
#pragma unroll
      for (int r = 0; r < 4; r++) acc[mi][ni][r] *= ei;
  }
  // ---- term2 (swapped): acc += P @ V^T (row=v, col=i) ----
  for (int j0 = 0; j0 < CHUNK_; j0 += 32) {
    __syncthreads();
    stage32(SB, vtbase + j0, N_, tid);           // rows v
    __syncthreads();
    if (wr == 1 || j0 < 64) {                    // wr==0 waves: i<64 -> j>=64 all masked
      bf16x8 af[4], bf[4];
#pragma unroll
      for (int mi = 0; mi < 4; mi++)
        af[mi] = *(const bf16x8*)&Ps[(wr * 64 + mi * 16 + l15) * 136 + j0 + q8];
#pragma unroll
      for (int ni = 0; ni < 4; ni++)
        bf[ni] = *(const bf16x8*)&SB[(wc * 64 + ni * 16 + l15) * 40 + q8];
#pragma unroll
      for (int mi = 0; mi < 4; mi++)
#pragma unroll
        for (int ni = 0; ni < 4; ni++)
          acc[mi][ni] = __builtin_amdgcn_mfma_f32_16x16x32_bf16(bf[ni], af[mi], acc[mi][ni], 0, 0, 0);
    }
  }
  // ---- write O (bf16, row-major [m][E]): u16x4 along v at fixed i ----
#pragma unroll
  for (int mi = 0; mi < 4; mi++) {
#pragma unroll
    for (int ni = 0; ni < 4; ni++) {
      int i = wr * 64 + mi * 16 + l15;
      int vb = wc * 64 + ni * 16 + q4i;
      u16x4 pk;
#pragma unroll
      for (int r = 0; r < 4; r++) pk[r] = f2b(acc[mi][ni][r]);
      *(u16x4*)&Ob[rowbase + (size_t)i * E_ + vb] = pk;
    }
  }
}

// ---------------------------------------------------------------------------
// o = o * gate (both bf16); LayerNorm(weight-only, fp32 gamma) -> bf16
// ---------------------------------------------------------------------------
__global__ void __launch_bounds__(256) gate_ln(const u16* __restrict__ O, const u16* __restrict__ G,
                                               const float* __restrict__ gamma, u16* __restrict__ OLN) {
  int row = blockIdx.x, tid = threadIdx.x;
  u16x4 o4 = *(const u16x4*)(O + (size_t)row * E_ + tid * 4);
  u16x4 g4 = *(const u16x4*)(G + (size_t)row * E_ + tid * 4);
  float x0 = b2f(o4[0]) * b2f(g4[0]), x1 = b2f(o4[1]) * b2f(g4[1]);
  float x2 = b2f(o4[2]) * b2f(g4[2]), x3 = b2f(o4[3]) * b2f(g4[3]);
  float s = x0 + x1 + x2 + x3;
  float sq = x0 * x0 + x1 * x1 + x2 * x2 + x3 * x3;
  __shared__ float red[8];
#pragma unroll
  for (int m = 1; m < 64; m <<= 1) { s += __shfl_xor(s, m); sq += __shfl_xor(sq, m); }
  int wid = tid >> 6;
  if ((tid & 63) == 0) { red[wid] = s; red[4 + wid] = sq; }
  __syncthreads();
  s = red[0] + red[1] + red[2] + red[3];
  sq = red[4] + red[5] + red[6] + red[7];
  float mu = s * (1.f / 1024.f);
  float var = sq * (1.f / 1024.f) - mu * mu;
  float rs = rsqrtf(var + 1e-5f);
  int e = tid * 4;
  u16x4 r4;
  r4[0] = f2b((x0 - mu) * rs * gamma[e + 0]);
  r4[1] = f2b((x1 - mu) * rs * gamma[e + 1]);
  r4[2] = f2b((x2 - mu) * rs * gamma[e + 2]);
  r4[3] = f2b((x3 - mu) * rs * gamma[e + 3]);
  *(u16x4*)(OLN + (size_t)row * E_ + e) = r4;
}

// ---------------------------------------------------------------------------
extern "C" void kernel_launch(void* const* d_in, const int* in_sizes, int n_in,
                              void* d_out, int out_size, void* d_ws, size_t ws_size,
                              hipStream_t stream) {
  (void)in_sizes; (void)n_in; (void)out_size; (void)ws_size;
  const float* x   = (const float*)d_in[0];
  const float* llb = (const float*)d_in[1];
  const float* Wq  = (const float*)d_in[2];
  const float* Wk  = (const float*)d_in[3];
  const float* Wv  = (const float*)d_in[4];
  const float* Wf  = (const float*)d_in[5];
  const float* Wb1 = (const float*)d_in[6];
  const float* Wb2 = (const float*)d_in[7];
  const float* Wg1 = (const float*)d_in[8];
  const float* Wg2 = (const float*)d_in[9];
  const float* gm  = (const float*)d_in[10];
  const float* Wo  = (const float*)d_in[11];
  float* out = (float*)d_out;

  char* ws = (char*)d_ws;
  const size_t SZB = (size_t)M_ * E_ * 2;            // 16.78 MB bf16 [M,E]
  u16*   Qb    = (u16*)(ws + 0 * SZB);               // q bf16 (OLN overlay later)
  u16*   Kb    = (u16*)(ws + 1 * SZB);
  u16*   KT    = (u16*)(ws + 2 * SZB);               // [B,H,R,N]
  u16*   VT    = (u16*)(ws + 3 * SZB);               // [B,H,R,N]
  u16*   BETAb = (u16*)(ws + 4 * SZB);               // beta -> O overlay
  u16*   GATEb = (u16*)(ws + 5 * SZB);
  u16*   SSb   = (u16*)(ws + 6 * SZB);               // chunk-start states bf16 [v][k]
  u16*   XB    = (u16*)(ws + 7 * SZB);
  u16*   U     = (u16*)(ws + 8 * SZB);               // bf16 [512][128][128]
  char*  tail  = ws + 8 * SZB + (size_t)BH_ * NC_ * R_ * R_ * 2;
  u16*   Wcat  = (u16*)tail;                         // [3456][1024]
  u16*   Wcat2 = Wcat + (size_t)3456 * 1024;         // [2048][256]
  u16*   WOb   = Wcat2 + (size_t)2048 * 256;         // [1024][1024]
  u16*   T1    = WOb + (size_t)E_ * E_;              // [M,256]
  float* LOGF  = (float*)(T1 + (size_t)M_ * 256);
  float* DC    = LOGF + (size_t)BH_ * N_;
  u16*   Ob    = BETAb;                              // overlay (beta dead after householder)
  u16*   OLN   = Qb;                                 // overlay (q dead after phaseC)

  CvtArgs ca;
  ca.src[0] = x;   ca.dst[0]  = XB;
  ca.src[1] = Wq;  ca.dst[1]  = Wcat;
  ca.src[2] = Wk;  ca.dst[2]  = Wcat + (size_t)1024 * 1024;
  ca.src[3] = Wv;  ca.dst[3]  = Wcat + (size_t)2048 * 1024;
  ca.src[4] = Wf;  ca.dst[4]  = Wcat + (size_t)3328 * 1024;
  ca.src[5] = Wb1; ca.dst[5]  = Wcat + (size_t)3072 * 1024;
  ca.src[6] = Wb2; ca.dst[6]  = Wcat2;
  ca.src[7] = Wg1; ca.dst[7]  = Wcat + (size_t)3200 * 1024;
  ca.src[8] = Wg2; ca.dst[8]  = Wcat2;
  ca.src[9] = Wo;  ca.dst[9]  = WOb;
  ca.dst[10] = Wcat + (size_t)3336 * 1024;           // zero pad rows

  dim3 blk(256);
  cvt_all<<<dim3(12928), blk, 0, stream>>>(ca);
  mega_gemm<<<dim3(1728), blk, 0, stream>>>(XB, Wcat, llb, Qb, Kb, KT, VT, T1, LOGF);
  bg_gemm<<<dim3(64, 16), blk, 0, stream>>>(T1, Wcat2, BETAb, GATEb);
  householder<<<dim3(M_), blk, 0, stream>>>(Qb, BETAb);
  gla_phaseA<<<dim3(BH_ * NC_), blk, 0, stream>>>(KT, VT, LOGF, U, DC);
  gla_phaseB<<<dim3(BH_ * 16384 / 256), blk, 0, stream>>>(U, DC, SSb);
  gla_phaseC<<<dim3(BH_ * NC_), blk, 0, stream>>>(Qb, Kb, VT, SSb, LOGF, Ob);
  gate_ln<<<dim3(M_), blk, 0, stream>>>(Ob, GATEb, gm, OLN);
  out_gemm<<<dim3(64, 8), blk, 0, stream>>>(OLN, WOb, out);
}